// Round 14
// baseline (257.636 us; speedup 1.0000x reference)
//
#include <hip/hip_runtime.h>
#include <math.h>

#define N_ATOMS 40000
#define N_EDGES 640000
#define NB      128
#define NRBF    20
#define NLAYERS 3
#define CUTOFF  5.0f
#define DELTA   (CUTOFF / 19.0f)
#define RBF_COEFF (-0.5f / (DELTA * DELTA))
#define LN2F    0.69314718055994531f

#define KTAB    256                     // lerp intervals over [0, CUTOFF]
#define TROWS   (KTAB + 2)              // rows 256,257 exact zero
#define TSCALE  ((float)KTAB / CUTOFF)
#define EPB     256                     // edges per block (4 waves x 64)
#define TAIL    96                      // staged look-ahead for tail walks
#define EBLKS   (N_EDGES / EPB)         // 2500
#define TABBLKS (TROWS / 2)             // 129

typedef __attribute__((ext_vector_type(8))) short bf16x8;
typedef __attribute__((ext_vector_type(4))) short bf16x4;
typedef __attribute__((ext_vector_type(4))) float fx4;

__device__ __forceinline__ float ssp_f(float x) {
    return fmaxf(x, 0.f) + __logf(1.f + __expf(-fabsf(x))) - LN2F;
}

__device__ __forceinline__ unsigned short bf16_rne(float x) {
    unsigned u = __float_as_uint(x);
    unsigned r = u + 0x7fffu + ((u >> 16) & 1u);
    return (unsigned short)(r >> 16);
}

__device__ __forceinline__ float bfl(unsigned u) { return __uint_as_float(u << 16); }
__device__ __forceinline__ float bfh(unsigned u) { return __uint_as_float(u & 0xffff0000u); }

// ---- GEMM building blocks (plain bf16) ----

// stage linear bf16 A-tile chunk -> swizzled LDS (no conversion)
__device__ __forceinline__ void stage_A_bf16(const unsigned short* __restrict__ A,
                                             int row0, int kc, short* Ah, int tid) {
    #pragma unroll
    for (int it = 0; it < 4; ++it) {
        int idx4 = tid + it * 256;
        int r = idx4 >> 4, kq = (idx4 & 15) << 2;
        bf16x4 v = *(const bf16x4*)(A + (size_t)(row0 + r) * NB + kc * 64 + kq);
        int wi = r * 64 + (kq ^ ((r & 7) << 3));
        *(bf16x4*)(Ah + wi) = v;
    }
}

__device__ __forceinline__ void stage_A_emb(const float* __restrict__ emb,
                                            const int* __restrict__ z, int row0, int kc,
                                            short* Ah, int tid) {
    #pragma unroll
    for (int it = 0; it < 4; ++it) {
        int idx4 = tid + it * 256;
        int r = idx4 >> 4, kq = (idx4 & 15) << 2;
        int zr = z[row0 + r];
        float4 v = *(const float4*)(emb + (size_t)zr * NB + kc * 64 + kq);
        bf16x4 hs;
        const float* vf = (const float*)&v;
        #pragma unroll
        for (int j = 0; j < 4; ++j) hs[j] = (short)bf16_rne(vf[j]);
        int wi = r * 64 + (kq ^ ((r & 7) << 3));
        *(bf16x4*)(Ah + wi) = hs;
    }
}

__device__ __forceinline__ void stage_W(const short* __restrict__ imgh,
                                        short* Wh, int tid) {
    #pragma unroll
    for (int it = 0; it < 4; ++it) {
        int i = tid + it * 256;
        ((bf16x8*)Wh)[i] = ((const bf16x8*)imgh)[i];
    }
}

__device__ __forceinline__ void stage_W_f32(const float* __restrict__ W, int kc,
                                            short* Wh, int tid) {
    #pragma unroll
    for (int it = 0; it < 8; ++it) {
        int i = tid + it * 256;
        int kl = i >> 5;
        int c0 = (i & 31) << 2;
        float4 v = *(const float4*)(W + (size_t)(kc * 64 + kl) * NB + c0);
        const float* vf = (const float*)&v;
        #pragma unroll
        for (int j = 0; j < 4; ++j) {
            int col = c0 + j;
            Wh[col * 64 + (kl ^ ((col & 7) << 3))] = (short)bf16_rne(vf[j]);
        }
    }
}

__device__ __forceinline__ void g_compute(const short* AH, int choff,
                                          const short* Wh,
                                          int wr, int wc, int lane, fx4 acc[2][4]) {
    #pragma unroll
    for (int ks = 0; ks < 2; ++ks) {
        int kb = ks * 32 + (lane >> 4) * 8;
        bf16x8 a_h[2];
        #pragma unroll
        for (int s = 0; s < 2; ++s) {
            int r = wr + s * 16 + (lane & 15);
            int idx = choff + r * 64 + (kb ^ ((r & 7) << 3));
            a_h[s] = *(const bf16x8*)(AH + idx);
        }
        #pragma unroll
        for (int c = 0; c < 4; ++c) {
            int col = wc + c * 16 + (lane & 15);
            int idx = col * 64 + (kb ^ ((col & 7) << 3));
            bf16x8 b_h = *(const bf16x8*)(Wh + idx);
            #pragma unroll
            for (int s = 0; s < 2; ++s)
                acc[s][c] = __builtin_amdgcn_mfma_f32_16x16x32_bf16(a_h[s], b_h, acc[s][c], 0, 0, 0);
        }
    }
}

// ---- k_pre0: layer-0 GEMM0 + table0 + dist/meta-pack + wprep(w=1..8) + AGGB zero ----
#define P0_GEMM 625
#define P0_TAB  TABBLKS
#define P0_DST  625
#define P0_WPR  64
#define P0_AGZ  625
__global__ __launch_bounds__(256) void k_pre0(const int* __restrict__ z,
                                              const float* __restrict__ emb,
                                              const float* __restrict__ r_ij,
                                              const int* __restrict__ ii,
                                              const int* __restrict__ jj,
                                              const float* __restrict__ in2f,
                                              const float* __restrict__ oW1,
                                              const float* __restrict__ oW2,
                                              const float* __restrict__ fW1,
                                              const float* __restrict__ fb1,
                                              const float* __restrict__ fW2,
                                              const float* __restrict__ fb2,
                                              unsigned short* __restrict__ HB,
                                              unsigned short* __restrict__ TabB,
                                              uint2* __restrict__ PK,
                                              unsigned short* __restrict__ AGGB,
                                              short* __restrict__ Wimg) {
    __shared__ short APOOL[12288];               // 24 KB
    int bid = blockIdx.x, tid = threadIdx.x;

    if (bid < P0_GEMM) {
        short* Ah = APOOL;
        short* Wh = APOOL + 4096;
        int wave = tid >> 6, lane = tid & 63;
        int wr = (wave & 1) * 32, wc = (wave >> 1) * 64;
        int row0 = bid * 64;
        fx4 acc[2][4];
        #pragma unroll
        for (int s = 0; s < 2; ++s)
            #pragma unroll
            for (int c = 0; c < 4; ++c)
                acc[s][c] = (fx4){0.f, 0.f, 0.f, 0.f};
        for (int kc = 0; kc < 2; ++kc) {
            if (kc) __syncthreads();
            stage_A_emb(emb, z, row0, kc, Ah, tid);
            stage_W_f32(in2f, kc, Wh, tid);
            __syncthreads();
            g_compute(Ah, 0, Wh, wr, wc, lane, acc);
        }
        #pragma unroll
        for (int s = 0; s < 2; ++s)
            #pragma unroll
            for (int c = 0; c < 4; ++c) {
                int colg = wc + c * 16 + (lane & 15);
                #pragma unroll
                for (int reg = 0; reg < 4; ++reg) {
                    int rowg = row0 + wr + s * 16 + (lane >> 4) * 4 + reg;
                    HB[(size_t)rowg * NB + colg] = bf16_rne(acc[s][c][reg]);
                }
            }
    } else if (bid < P0_GEMM + P0_TAB) {
        int tb = bid - P0_GEMM;
        int half = tid >> 7, f = tid & 127;
        int r = tb * 2 + half;                   // 0..257
        float* tl = (float*)APOOL;
        float val = 0.f;
        float d = (float)r * (CUTOFF / (float)KTAB);
        if (r < KTAB) {
            float a = fb1[f];
            #pragma unroll
            for (int q = 0; q < NRBF; ++q) {
                float dr = d - (float)q * DELTA;
                a += __expf(RBF_COEFF * dr * dr) * fW1[q * NB + f];
            }
            tl[half * NB + f] = ssp_f(a);
        }
        __syncthreads();
        if (r < KTAB) {
            float w = fb2[f];
            #pragma unroll 4
            for (int k = 0; k < NB; ++k) w += tl[half * NB + k] * fW2[k * NB + f];
            float rc = 0.5f * (__cosf(d * ((float)M_PI / CUTOFF)) + 1.f);
            val = w * rc;
        }
        TabB[(size_t)r * NB + f] = bf16_rne(val);
    } else if (bid < P0_GEMM + P0_TAB + P0_DST) {
        int e = (bid - (P0_GEMM + P0_TAB)) * 1024 + tid * 4;
        const float4* rv = (const float4*)(r_ij + (size_t)e * 3);
        float4 a = rv[0], b = rv[1], c = rv[2];
        int4 iv = *(const int4*)(ii + e);
        int4 jv = *(const int4*)(jj + e);
        float d0 = sqrtf(a.x * a.x + a.y * a.y + a.z * a.z);
        float d1 = sqrtf(a.w * a.w + b.x * b.x + b.y * b.y);
        float d2 = sqrtf(b.z * b.z + b.w * b.w + c.x * c.x);
        float d3 = sqrtf(c.y * c.y + c.z * c.z + c.w * c.w);
        float u0 = fminf(d0 * TSCALE, (float)KTAB);
        float u1 = fminf(d1 * TSCALE, (float)KTAB);
        float u2 = fminf(d2 * TSCALE, (float)KTAB);
        float u3 = fminf(d3 * TSCALE, (float)KTAB);
        uint4 w0, w1;
        w0.x = __float_as_uint(u0); w0.y = ((unsigned)iv.x << 16) | (unsigned)jv.x;
        w0.z = __float_as_uint(u1); w0.w = ((unsigned)iv.y << 16) | (unsigned)jv.y;
        w1.x = __float_as_uint(u2); w1.y = ((unsigned)iv.z << 16) | (unsigned)jv.z;
        w1.z = __float_as_uint(u3); w1.w = ((unsigned)iv.w << 16) | (unsigned)jv.w;
        *(uint4*)(PK + e) = w0;
        *(uint4*)(PK + e + 2) = w1;
    } else if (bid < P0_GEMM + P0_TAB + P0_DST + P0_WPR) {
        int b2 = bid - (P0_GEMM + P0_TAB + P0_DST);             // 0..63
        int w = 1 + (b2 >> 3), seg = b2 & 7;                    // images 1..8
        int layer = w / 3, which = w % 3;
        const float* W = (which == 0 ? in2f : which == 1 ? oW1 : oW2)
                         + (size_t)layer * NB * NB;
        short* hi = Wimg + (size_t)w * 16384;
        int i0 = seg * 2048;
        #pragma unroll
        for (int ofs = 0; ofs < 2048; ofs += 256) {
            int i = i0 + ofs + tid;
            int k = i >> 7, col = i & 127;
            int kc = k >> 6, kl = k & 63;
            hi[kc * 8192 + col * 64 + (kl ^ ((col & 7) << 3))] = (short)bf16_rne(W[i]);
        }
    } else {
        // zero AGGB (bf16): rows of edgeless atoms stay zero for all layers
        int base = (bid - (P0_GEMM + P0_TAB + P0_DST + P0_WPR)) * 8192 + tid * 32;
        uint4 zv = make_uint4(0u, 0u, 0u, 0u);
        uint4* p = (uint4*)(AGGB + base);
        p[0] = zv; p[1] = zv; p[2] = zv; p[3] = zv;
    }
}

// ---- edge kernel: dual-stream segment-start ownership, pure bf16 stores ----
__global__ __launch_bounds__(256) void k_edge(const uint2* __restrict__ PK,
                                              const unsigned* __restrict__ HBv,
                                              const unsigned* __restrict__ TabU,
                                              unsigned short* __restrict__ AGGB,
                                              const float* __restrict__ nW1,
                                              const float* __restrict__ nb1,
                                              const float* __restrict__ nW2,
                                              const float* __restrict__ nb2,
                                              unsigned short* __restrict__ TabN) {
    __shared__ uint2 m_s[EPB + TAIL];          // 2816 B
    __shared__ float t_lds[256];
    int tid = threadIdx.x;
    int bid = blockIdx.x;

    if (bid >= EBLKS) {                        // next-layer table block
        int tb = bid - EBLKS;
        int half = tid >> 7, f = tid & 127;
        int r = tb * 2 + half;                 // 0..257
        float val = 0.f;
        float d = (float)r * (CUTOFF / (float)KTAB);
        if (r < KTAB) {
            float a = nb1[f];
            #pragma unroll
            for (int q = 0; q < NRBF; ++q) {
                float dr = d - (float)q * DELTA;
                a += __expf(RBF_COEFF * dr * dr) * nW1[q * NB + f];
            }
            t_lds[half * NB + f] = ssp_f(a);
        }
        __syncthreads();
        if (r < KTAB) {
            float w = nb2[f];
            #pragma unroll 4
            for (int k = 0; k < NB; ++k) w += t_lds[half * NB + k] * nW2[k * NB + f];
            float rc = 0.5f * (__cosf(d * ((float)M_PI / CUTOFF)) + 1.f);
            val = w * rc;
        }
        TabN[(size_t)r * NB + f] = bf16_rne(val);
        return;
    }

    int e0 = bid * EPB;
    m_s[tid] = PK[e0 + tid];
    if (tid < TAIL) {
        int g = e0 + EPB + tid;
        m_s[EPB + tid] = (g < N_EDGES) ? PK[g] : make_uint2(0u, 0xFFFF0000u);
    }
    __syncthreads();

    int wave = tid >> 6, lane = tid & 63;
    int wl = wave << 6;

    int gA = e0 + wl;
    int prevA = (gA > 0) ? (int)(PK[gA - 1].y >> 16) : -1;   // wave-uniform
    int prevB = (int)(m_s[wl + 31].y >> 16);

    float axA = 0.f, ayA = 0.f, axB = 0.f, ayB = 0.f;
    int curA = -1, curB = -1;

    #pragma unroll 2
    for (int t = 0; t < 32; ++t) {
        uint2 mA = m_s[wl + t];
        uint2 mB = m_s[wl + 32 + t];
        int iaA = (int)(mA.y >> 16);
        int iaB = (int)(mB.y >> 16);

        if (iaA != prevA) {                    // head edges owned upstream
            float u = __uint_as_float(mA.x);
            int k = (int)u;
            float fr = u - (float)k;
            int ja = (int)(mA.y & 0xffffu);
            unsigned t0 = TabU[k * 64 + lane];
            unsigned t1 = TabU[k * 64 + 64 + lane];
            unsigned hq = HBv[ja * 64 + lane];
            float w0 = fmaf(fr, bfl(t1) - bfl(t0), bfl(t0));
            float w1 = fmaf(fr, bfh(t1) - bfh(t0), bfh(t0));
            if (iaA != curA) {                 // wave-uniform; segment wave-owned
                if (curA >= 0) {
                    unsigned pk2 = (unsigned)bf16_rne(axA) | ((unsigned)bf16_rne(ayA) << 16);
                    *(unsigned*)(AGGB + (size_t)curA * NB + 2 * lane) = pk2;
                }
                axA = 0.f; ayA = 0.f;
                curA = iaA;
            }
            axA = fmaf(bfl(hq), w0, axA);
            ayA = fmaf(bfh(hq), w1, ayA);
        }

        if (iaB != prevB) {
            float u = __uint_as_float(mB.x);
            int k = (int)u;
            float fr = u - (float)k;
            int ja = (int)(mB.y & 0xffffu);
            unsigned t0 = TabU[k * 64 + lane];
            unsigned t1 = TabU[k * 64 + 64 + lane];
            unsigned hq = HBv[ja * 64 + lane];
            float w0 = fmaf(fr, bfl(t1) - bfl(t0), bfl(t0));
            float w1 = fmaf(fr, bfh(t1) - bfh(t0), bfh(t0));
            if (iaB != curB) {
                if (curB >= 0) {
                    unsigned pk2 = (unsigned)bf16_rne(axB) | ((unsigned)bf16_rne(ayB) << 16);
                    *(unsigned*)(AGGB + (size_t)curB * NB + 2 * lane) = pk2;
                }
                axB = 0.f; ayB = 0.f;
                curB = iaB;
            }
            axB = fmaf(bfl(hq), w0, axB);
            ayB = fmaf(bfh(hq), w1, ayB);
        }
    }

    // interleaved tail walks (independent cursors -> 2-way ILP persists)
    int pA = wl + 32, pB = wl + 64;
    bool actA = (curA >= 0), actB = (curB >= 0);
    while (actA || actB) {
        if (actA) {
            bool cont = false;
            uint2 m;
            if (pA < EPB + TAIL) {
                m = m_s[pA];
                cont = ((int)(m.y >> 16) == curA);
            }
            if (cont) {
                float u = __uint_as_float(m.x);
                int k = (int)u;
                float fr = u - (float)k;
                int ja = (int)(m.y & 0xffffu);
                unsigned t0 = TabU[k * 64 + lane];
                unsigned t1 = TabU[k * 64 + 64 + lane];
                unsigned hq = HBv[ja * 64 + lane];
                float w0 = fmaf(fr, bfl(t1) - bfl(t0), bfl(t0));
                float w1 = fmaf(fr, bfh(t1) - bfh(t0), bfh(t0));
                axA = fmaf(bfl(hq), w0, axA);
                ayA = fmaf(bfh(hq), w1, ayA);
                ++pA;
            } else {
                unsigned pk2 = (unsigned)bf16_rne(axA) | ((unsigned)bf16_rne(ayA) << 16);
                *(unsigned*)(AGGB + (size_t)curA * NB + 2 * lane) = pk2;
                actA = false;
            }
        }
        if (actB) {
            bool cont = false;
            uint2 m;
            if (pB < EPB + TAIL) {
                m = m_s[pB];
                cont = ((int)(m.y >> 16) == curB);
            }
            if (cont) {
                float u = __uint_as_float(m.x);
                int k = (int)u;
                float fr = u - (float)k;
                int ja = (int)(m.y & 0xffffu);
                unsigned t0 = TabU[k * 64 + lane];
                unsigned t1 = TabU[k * 64 + 64 + lane];
                unsigned hq = HBv[ja * 64 + lane];
                float w0 = fmaf(fr, bfl(t1) - bfl(t0), bfl(t0));
                float w1 = fmaf(fr, bfh(t1) - bfh(t0), bfh(t0));
                axB = fmaf(bfl(hq), w0, axB);
                ayB = fmaf(bfh(hq), w1, ayB);
                ++pB;
            } else {
                unsigned pk2 = (unsigned)bf16_rne(axB) | ((unsigned)bf16_rne(ayB) << 16);
                *(unsigned*)(AGGB + (size_t)curB * NB + 2 * lane) = pk2;
                actB = false;
            }
        }
    }
}

// ---- k_fuse: X (+)= ssp(AGGB@W1+b1)@W2+b2, then HB = bf16(X_new @ in2f_next) ----
template<int FIRST, int LAST>
__global__ __launch_bounds__(256) void k_fuse(const unsigned short* __restrict__ AGGB,
                                              const short* __restrict__ img1,
                                              const float* __restrict__ b1,
                                              const short* __restrict__ img2,
                                              const float* __restrict__ b2,
                                              const short* __restrict__ img0n,
                                              const int* __restrict__ z,
                                              const float* __restrict__ emb,
                                              float* __restrict__ X,
                                              unsigned short* __restrict__ HB) {
    __shared__ short POOL[16384];              // 32 KB
    short* Ah = POOL;
    short* Th = POOL;
    short* Wh = POOL + 8192;

    int tid = threadIdx.x;
    int wave = tid >> 6, lane = tid & 63;
    int wr = (wave & 1) * 32, wc = (wave >> 1) * 64;
    int row0 = blockIdx.x * 64;

    fx4 accT[2][4];
    #pragma unroll
    for (int s = 0; s < 2; ++s)
        #pragma unroll
        for (int c = 0; c < 4; ++c)
            accT[s][c] = (fx4){0.f, 0.f, 0.f, 0.f};
    for (int kc = 0; kc < 2; ++kc) {
        if (kc) __syncthreads();
        stage_A_bf16(AGGB, row0, kc, Ah, tid);
        stage_W(img1 + kc * 8192, Wh, tid);
        __syncthreads();
        g_compute(Ah, 0, Wh, wr, wc, lane, accT);
    }
    __syncthreads();

    #pragma unroll
    for (int s = 0; s < 2; ++s)
        #pragma unroll
        for (int c = 0; c < 4; ++c) {
            int colg = wc + c * 16 + (lane & 15);
            float bv = b1[colg];
            int kc2 = colg >> 6, kl = colg & 63;
            #pragma unroll
            for (int reg = 0; reg < 4; ++reg) {
                int rl = wr + s * 16 + (lane >> 4) * 4 + reg;
                float t = ssp_f(accT[s][c][reg] + bv);
                Th[kc2 * 4096 + rl * 64 + (kl ^ ((rl & 7) << 3))] = (short)bf16_rne(t);
            }
        }
    stage_W(img2, Wh, tid);
    __syncthreads();

    fx4 accV[2][4];
    #pragma unroll
    for (int s = 0; s < 2; ++s)
        #pragma unroll
        for (int c = 0; c < 4; ++c)
            accV[s][c] = (fx4){0.f, 0.f, 0.f, 0.f};
    g_compute(Th, 0, Wh, wr, wc, lane, accV);
    __syncthreads();
    stage_W(img2 + 8192, Wh, tid);
    __syncthreads();
    g_compute(Th, 4096, Wh, wr, wc, lane, accV);
    __syncthreads();

    #pragma unroll
    for (int s = 0; s < 2; ++s)
        #pragma unroll
        for (int c = 0; c < 4; ++c) {
            int colg = wc + c * 16 + (lane & 15);
            float bv = b2[colg];
            int kc2 = colg >> 6, kl = colg & 63;
            #pragma unroll
            for (int reg = 0; reg < 4; ++reg) {
                int rowg = row0 + wr + s * 16 + (lane >> 4) * 4 + reg;
                size_t o = (size_t)rowg * NB + colg;
                float xo;
                if (FIRST) xo = emb[(size_t)z[rowg] * NB + colg];
                else       xo = X[o];
                float xn = xo + accV[s][c][reg] + bv;
                X[o] = xn;
                if (!LAST) {
                    int rl = wr + s * 16 + (lane >> 4) * 4 + reg;
                    Th[kc2 * 4096 + rl * 64 + (kl ^ ((rl & 7) << 3))] = (short)bf16_rne(xn);
                }
            }
        }
    if (LAST) return;

    stage_W(img0n, Wh, tid);
    __syncthreads();
    fx4 accH[2][4];
    #pragma unroll
    for (int s = 0; s < 2; ++s)
        #pragma unroll
        for (int c = 0; c < 4; ++c)
            accH[s][c] = (fx4){0.f, 0.f, 0.f, 0.f};
    g_compute(Th, 0, Wh, wr, wc, lane, accH);
    __syncthreads();
    stage_W(img0n + 8192, Wh, tid);
    __syncthreads();
    g_compute(Th, 4096, Wh, wr, wc, lane, accH);

    #pragma unroll
    for (int s = 0; s < 2; ++s)
        #pragma unroll
        for (int c = 0; c < 4; ++c) {
            int colg = wc + c * 16 + (lane & 15);
            #pragma unroll
            for (int reg = 0; reg < 4; ++reg) {
                int rowg = row0 + wr + s * 16 + (lane >> 4) * 4 + reg;
                HB[(size_t)rowg * NB + colg] = bf16_rne(accH[s][c][reg]);
            }
        }
}

extern "C" void kernel_launch(void* const* d_in, const int* in_sizes, int n_in,
                              void* d_out, int out_size, void* d_ws, size_t ws_size,
                              hipStream_t stream) {
    const int*   z    = (const int*)  d_in[0];
    const float* rij  = (const float*)d_in[1];
    const int*   ii   = (const int*)  d_in[2];
    const int*   jj   = (const int*)  d_in[3];
    const float* emb  = (const float*)d_in[4];
    const float* in2f = (const float*)d_in[5];
    const float* fW1  = (const float*)d_in[6];
    const float* fb1  = (const float*)d_in[7];
    const float* fW2  = (const float*)d_in[8];
    const float* fb2  = (const float*)d_in[9];
    const float* oW1  = (const float*)d_in[10];
    const float* ob1  = (const float*)d_in[11];
    const float* oW2  = (const float*)d_in[12];
    const float* ob2  = (const float*)d_in[13];

    const int NXF = N_ATOMS * NB;

    float* X = (float*)d_out;
    unsigned short* HB   = (unsigned short*)d_ws;               // [N_ATOMS][NB] bf16
    unsigned short* AGGB = HB + (size_t)NXF;                    // [N_ATOMS][NB] bf16
    uint2*          PK   = (uint2*)(AGGB + (size_t)NXF);        // [N_EDGES] {u, i<<16|j}
    unsigned short* Tab0 = (unsigned short*)(PK + N_EDGES);     // [258][NB] bf16
    unsigned short* Tab1 = Tab0 + (size_t)TROWS * NB;
    short*          Wimg = (short*)(Tab1 + (size_t)TROWS * NB); // 9 x 16384 (w=0 unused)

    k_pre0<<<P0_GEMM + P0_TAB + P0_DST + P0_WPR + P0_AGZ, 256, 0, stream>>>(
        z, emb, rij, ii, jj, in2f, oW1, oW2,
        fW1, fb1, fW2, fb2, HB, Tab0, PK, AGGB, Wimg);

    for (int l = 0; l < NLAYERS; ++l) {
        unsigned short* TabCur = (l & 1) ? Tab1 : Tab0;
        unsigned short* TabNxt = (l & 1) ? Tab0 : Tab1;
        int ln = (l < NLAYERS - 1) ? l + 1 : 0;
        int grid_e = EBLKS + ((l < NLAYERS - 1) ? TABBLKS : 0);

        k_edge<<<grid_e, 256, 0, stream>>>(PK,
                                           (const unsigned*)HB,
                                           (const unsigned*)TabCur,
                                           AGGB,
                                           fW1 + (size_t)ln * NRBF * NB,
                                           fb1 + (size_t)ln * NB,
                                           fW2 + (size_t)ln * NB * NB,
                                           fb2 + (size_t)ln * NB,
                                           TabNxt);

        const short* img1  = Wimg + (size_t)(l * 3 + 1) * 16384;
        const short* img2  = Wimg + (size_t)(l * 3 + 2) * 16384;
        const short* img0n = Wimg + (size_t)((l + 1 < NLAYERS ? (l + 1) * 3 : 3)) * 16384;

        if (l == 0)
            k_fuse<1, 0><<<N_ATOMS / 64, 256, 0, stream>>>(AGGB, img1, ob1 + (size_t)l * NB,
                                                           img2, ob2 + (size_t)l * NB,
                                                           img0n, z, emb, X, HB);
        else if (l < NLAYERS - 1)
            k_fuse<0, 0><<<N_ATOMS / 64, 256, 0, stream>>>(AGGB, img1, ob1 + (size_t)l * NB,
                                                           img2, ob2 + (size_t)l * NB,
                                                           img0n, z, emb, X, HB);
        else
            k_fuse<0, 1><<<N_ATOMS / 64, 256, 0, stream>>>(AGGB, img1, ob1 + (size_t)l * NB,
                                                           img2, ob2 + (size_t)l * NB,
                                                           img0n, z, emb, X, HB);
    }
}

// Round 15
// 214.473 us; speedup vs baseline: 1.2013x; 1.2013x over previous
//
#include <hip/hip_runtime.h>
#include <math.h>

#define N_ATOMS 40000
#define N_EDGES 640000
#define NB      128
#define NRBF    20
#define NLAYERS 3
#define CUTOFF  5.0f
#define DELTA   (CUTOFF / 19.0f)
#define RBF_COEFF (-0.5f / (DELTA * DELTA))
#define LN2F    0.69314718055994531f

#define KTAB    256                     // lerp intervals over [0, CUTOFF]
#define TROWS   (KTAB + 2)              // rows 256,257 exact zero
#define TSCALE  ((float)KTAB / CUTOFF)
#define EPB     256                     // edges per block (4 waves x 64)
#define EBLKS   (N_EDGES / EPB)         // 2500
#define TABBLKS (TROWS / 2)             // 129

typedef __attribute__((ext_vector_type(8))) short bf16x8;
typedef __attribute__((ext_vector_type(4))) short bf16x4;
typedef __attribute__((ext_vector_type(4))) float fx4;

__device__ __forceinline__ float ssp_f(float x) {
    return fmaxf(x, 0.f) + __logf(1.f + __expf(-fabsf(x))) - LN2F;
}

__device__ __forceinline__ unsigned short bf16_rne(float x) {
    unsigned u = __float_as_uint(x);
    unsigned r = u + 0x7fffu + ((u >> 16) & 1u);
    return (unsigned short)(r >> 16);
}

__device__ __forceinline__ float bfl(unsigned u) { return __uint_as_float(u << 16); }
__device__ __forceinline__ float bfh(unsigned u) { return __uint_as_float(u & 0xffff0000u); }

// ---- GEMM building blocks (plain bf16) ----

// stage AGG chunk and zero it behind the read (next-layer prep)
template<int ZERO>
__device__ __forceinline__ void stage_A_agg(float* __restrict__ A, int row0, int kc,
                                            short* Ah, int tid) {
    #pragma unroll
    for (int it = 0; it < 4; ++it) {
        int idx4 = tid + it * 256;
        int r = idx4 >> 4, kq = (idx4 & 15) << 2;
        float* src = A + (size_t)(row0 + r) * NB + kc * 64 + kq;
        float4 v = *(const float4*)src;
        if (ZERO) *(float4*)src = make_float4(0.f, 0.f, 0.f, 0.f);
        bf16x4 hs;
        const float* vf = (const float*)&v;
        #pragma unroll
        for (int j = 0; j < 4; ++j) hs[j] = (short)bf16_rne(vf[j]);
        int wi = r * 64 + (kq ^ ((r & 7) << 3));
        *(bf16x4*)(Ah + wi) = hs;
    }
}

// stage A from embedding gather (layer 0 GEMM0)
__device__ __forceinline__ void stage_A_emb(const float* __restrict__ emb,
                                            const int* __restrict__ z, int row0, int kc,
                                            short* Ah, int tid) {
    #pragma unroll
    for (int it = 0; it < 4; ++it) {
        int idx4 = tid + it * 256;
        int r = idx4 >> 4, kq = (idx4 & 15) << 2;
        int zr = z[row0 + r];
        float4 v = *(const float4*)(emb + (size_t)zr * NB + kc * 64 + kq);
        bf16x4 hs;
        const float* vf = (const float*)&v;
        #pragma unroll
        for (int j = 0; j < 4; ++j) hs[j] = (short)bf16_rne(vf[j]);
        int wi = r * 64 + (kq ^ ((r & 7) << 3));
        *(bf16x4*)(Ah + wi) = hs;
    }
}

// copy one pre-swizzled weight chunk image (128 cols x 64 k) to LDS
__device__ __forceinline__ void stage_W(const short* __restrict__ imgh,
                                        short* Wh, int tid) {
    #pragma unroll
    for (int it = 0; it < 4; ++it) {
        int i = tid + it * 256;
        ((bf16x8*)Wh)[i] = ((const bf16x8*)imgh)[i];
    }
}

// stage W chunk directly from fp32 W[k][col] (layer-0 GEMM0 only)
__device__ __forceinline__ void stage_W_f32(const float* __restrict__ W, int kc,
                                            short* Wh, int tid) {
    #pragma unroll
    for (int it = 0; it < 8; ++it) {
        int i = tid + it * 256;
        int kl = i >> 5;
        int c0 = (i & 31) << 2;
        float4 v = *(const float4*)(W + (size_t)(kc * 64 + kl) * NB + c0);
        const float* vf = (const float*)&v;
        #pragma unroll
        for (int j = 0; j < 4; ++j) {
            int col = c0 + j;
            Wh[col * 64 + (kl ^ ((col & 7) << 3))] = (short)bf16_rne(vf[j]);
        }
    }
}

// one K=64 chunk of bf16 MFMA: acc += A_chunk @ W_chunk (16 MFMA/wave)
__device__ __forceinline__ void g_compute(const short* AH, int choff,
                                          const short* Wh,
                                          int wr, int wc, int lane, fx4 acc[2][4]) {
    #pragma unroll
    for (int ks = 0; ks < 2; ++ks) {
        int kb = ks * 32 + (lane >> 4) * 8;
        bf16x8 a_h[2];
        #pragma unroll
        for (int s = 0; s < 2; ++s) {
            int r = wr + s * 16 + (lane & 15);
            int idx = choff + r * 64 + (kb ^ ((r & 7) << 3));
            a_h[s] = *(const bf16x8*)(AH + idx);
        }
        #pragma unroll
        for (int c = 0; c < 4; ++c) {
            int col = wc + c * 16 + (lane & 15);
            int idx = col * 64 + (kb ^ ((col & 7) << 3));
            bf16x8 b_h = *(const bf16x8*)(Wh + idx);
            #pragma unroll
            for (int s = 0; s < 2; ++s)
                acc[s][c] = __builtin_amdgcn_mfma_f32_16x16x32_bf16(a_h[s], b_h, acc[s][c], 0, 0, 0);
        }
    }
}

// ---- k_pre0: layer-0 GEMM0 + zero AGG + table0 + dist + wprep(w=1..8) ----
#define P0_GEMM 625
#define P0_ZERO 1250
#define P0_TAB  TABBLKS
#define P0_DST  625
#define P0_WPR  64
__global__ __launch_bounds__(256) void k_pre0(const int* __restrict__ z,
                                              const float* __restrict__ emb,
                                              const float* __restrict__ r_ij,
                                              const float* __restrict__ in2f,
                                              const float* __restrict__ oW1,
                                              const float* __restrict__ oW2,
                                              const float* __restrict__ fW1,
                                              const float* __restrict__ fb1,
                                              const float* __restrict__ fW2,
                                              const float* __restrict__ fb2,
                                              unsigned short* __restrict__ HB,
                                              unsigned short* __restrict__ TabB,
                                              float* __restrict__ AGG,
                                              float* __restrict__ U,
                                              short* __restrict__ Wimg) {
    __shared__ short APOOL[12288];               // 24 KB
    int bid = blockIdx.x, tid = threadIdx.x;

    if (bid < P0_GEMM) {
        short* Ah = APOOL;
        short* Wh = APOOL + 4096;
        int wave = tid >> 6, lane = tid & 63;
        int wr = (wave & 1) * 32, wc = (wave >> 1) * 64;
        int row0 = bid * 64;
        fx4 acc[2][4];
        #pragma unroll
        for (int s = 0; s < 2; ++s)
            #pragma unroll
            for (int c = 0; c < 4; ++c)
                acc[s][c] = (fx4){0.f, 0.f, 0.f, 0.f};
        for (int kc = 0; kc < 2; ++kc) {
            if (kc) __syncthreads();
            stage_A_emb(emb, z, row0, kc, Ah, tid);
            stage_W_f32(in2f, kc, Wh, tid);
            __syncthreads();
            g_compute(Ah, 0, Wh, wr, wc, lane, acc);
        }
        #pragma unroll
        for (int s = 0; s < 2; ++s)
            #pragma unroll
            for (int c = 0; c < 4; ++c) {
                int colg = wc + c * 16 + (lane & 15);
                #pragma unroll
                for (int reg = 0; reg < 4; ++reg) {
                    int rowg = row0 + wr + s * 16 + (lane >> 4) * 4 + reg;
                    HB[(size_t)rowg * NB + colg] = bf16_rne(acc[s][c][reg]);
                }
            }
    } else if (bid < P0_GEMM + P0_ZERO) {
        int base = (bid - P0_GEMM) * 4096 + tid * 16;
        float4 zv = make_float4(0.f, 0.f, 0.f, 0.f);
        float4* p = (float4*)(AGG + base);
        p[0] = zv; p[1] = zv; p[2] = zv; p[3] = zv;
    } else if (bid < P0_GEMM + P0_ZERO + P0_TAB) {
        int tb = bid - (P0_GEMM + P0_ZERO);
        int half = tid >> 7, f = tid & 127;
        int r = tb * 2 + half;                   // 0..257
        float* tl = (float*)APOOL;               // [2][128] ssp intermediates
        float val = 0.f;
        float d = (float)r * (CUTOFF / (float)KTAB);
        if (r < KTAB) {
            float a = fb1[f];
            #pragma unroll
            for (int q = 0; q < NRBF; ++q) {
                float dr = d - (float)q * DELTA;
                a += __expf(RBF_COEFF * dr * dr) * fW1[q * NB + f];
            }
            tl[half * NB + f] = ssp_f(a);
        }
        __syncthreads();
        if (r < KTAB) {
            float w = fb2[f];
            #pragma unroll 4
            for (int k = 0; k < NB; ++k) w += tl[half * NB + k] * fW2[k * NB + f];
            float rc = 0.5f * (__cosf(d * ((float)M_PI / CUTOFF)) + 1.f);
            val = w * rc;
        }
        TabB[(size_t)r * NB + f] = bf16_rne(val);
    } else if (bid < P0_GEMM + P0_ZERO + P0_TAB + P0_DST) {
        int e = (bid - (P0_GEMM + P0_ZERO + P0_TAB)) * 1024 + tid * 4;
        const float4* rv = (const float4*)(r_ij + (size_t)e * 3);
        float4 a = rv[0], b = rv[1], c = rv[2];
        float d0 = sqrtf(a.x * a.x + a.y * a.y + a.z * a.z);
        float d1 = sqrtf(a.w * a.w + b.x * b.x + b.y * b.y);
        float d2 = sqrtf(b.z * b.z + b.w * b.w + c.x * c.x);
        float d3 = sqrtf(c.y * c.y + c.z * c.z + c.w * c.w);
        *(float4*)(U + e) = make_float4(d0 * TSCALE, d1 * TSCALE, d2 * TSCALE, d3 * TSCALE);
    } else {
        int b2 = bid - (P0_GEMM + P0_ZERO + P0_TAB + P0_DST);   // 0..63
        int w = 1 + (b2 >> 3), seg = b2 & 7;                    // images 1..8
        int layer = w / 3, which = w % 3;
        const float* W = (which == 0 ? in2f : which == 1 ? oW1 : oW2)
                         + (size_t)layer * NB * NB;
        short* hi = Wimg + (size_t)w * 16384;
        int i0 = seg * 2048;
        #pragma unroll
        for (int ofs = 0; ofs < 2048; ofs += 256) {
            int i = i0 + ofs + tid;
            int k = i >> 7, col = i & 127;
            int kc = k >> 6, kl = k & 63;
            hi[kc * 8192 + col * 64 + (kl ^ ((col & 7) << 3))] = (short)bf16_rne(W[i]);
        }
    }
}

// ---- edge kernel (R8-proven form): dual-stream, two-row bf16 lerp, boundary
//      atomics + interior plain stores; appended next-layer table blocks ----
__global__ __launch_bounds__(256) void k_edge(const float* __restrict__ U,
                                              const int* __restrict__ idx_i,
                                              const int* __restrict__ idx_j,
                                              const unsigned* __restrict__ HBv,
                                              const unsigned* __restrict__ TabU,
                                              float* __restrict__ AGG,
                                              const float* __restrict__ nW1,
                                              const float* __restrict__ nb1,
                                              const float* __restrict__ nW2,
                                              const float* __restrict__ nb2,
                                              unsigned short* __restrict__ TabN) {
    __shared__ float u_s[EPB];
    __shared__ int   i_s[EPB];
    __shared__ int   j_s[EPB];
    __shared__ float t_lds[256];
    int tid = threadIdx.x;
    int bid = blockIdx.x;

    if (bid >= EBLKS) {                        // next-layer table block
        int tb = bid - EBLKS;
        int half = tid >> 7, f = tid & 127;
        int r = tb * 2 + half;                 // 0..257
        float val = 0.f;
        float d = (float)r * (CUTOFF / (float)KTAB);
        if (r < KTAB) {
            float a = nb1[f];
            #pragma unroll
            for (int q = 0; q < NRBF; ++q) {
                float dr = d - (float)q * DELTA;
                a += __expf(RBF_COEFF * dr * dr) * nW1[q * NB + f];
            }
            t_lds[half * NB + f] = ssp_f(a);
        }
        __syncthreads();
        if (r < KTAB) {
            float w = nb2[f];
            #pragma unroll 4
            for (int k = 0; k < NB; ++k) w += t_lds[half * NB + k] * nW2[k * NB + f];
            float rc = 0.5f * (__cosf(d * ((float)M_PI / CUTOFF)) + 1.f);
            val = w * rc;
        }
        TabN[(size_t)r * NB + f] = bf16_rne(val);
        return;
    }

    int e0 = bid * EPB;
    u_s[tid] = U[e0 + tid];
    i_s[tid] = idx_i[e0 + tid];
    j_s[tid] = idx_j[e0 + tid];
    __syncthreads();

    int wave = tid >> 6, lane = tid & 63;
    int wbase = wave << 6;

    float axA = 0.f, ayA = 0.f, axB = 0.f, ayB = 0.f;
    int curA = -1, curB = -1;
    int nfA = 0, nfB = 0;

    #pragma unroll 2
    for (int t = 0; t < 32; ++t) {
        int eA = wbase + t;
        int eB = wbase + 32 + t;
        float uA = u_s[eA], uB = u_s[eB];
        int   iaA = i_s[eA], iaB = i_s[eB];
        int   jaA = j_s[eA], jaB = j_s[eB];

        int kA = (int)uA; kA = (kA > KTAB) ? KTAB : kA;
        int kB = (int)uB; kB = (kB > KTAB) ? KTAB : kB;
        float frA = uA - (float)kA;
        float frB = uB - (float)kB;

        unsigned v0A = TabU[kA * 64 + lane];
        unsigned v1A = TabU[kA * 64 + 64 + lane];
        unsigned v0B = TabU[kB * 64 + lane];
        unsigned v1B = TabU[kB * 64 + 64 + lane];
        unsigned hqA = HBv[jaA * 64 + lane];
        unsigned hqB = HBv[jaB * 64 + lane];

        float w0A = fmaf(frA, bfl(v1A) - bfl(v0A), bfl(v0A));
        float w1A = fmaf(frA, bfh(v1A) - bfh(v0A), bfh(v0A));
        float w0B = fmaf(frB, bfl(v1B) - bfl(v0B), bfl(v0B));
        float w1B = fmaf(frB, bfh(v1B) - bfh(v0B), bfh(v0B));

        if (iaA != curA) {                     // wave-uniform
            if (curA >= 0) {
                float* p = AGG + (size_t)curA * NB + 2 * lane;
                if (nfA == 0) { atomicAdd(p, axA); atomicAdd(p + 1, ayA); }
                else          { *(float2*)p = make_float2(axA, ayA); }
                ++nfA;
            }
            axA = 0.f; ayA = 0.f;
            curA = iaA;
        }
        axA = fmaf(bfl(hqA), w0A, axA);
        ayA = fmaf(bfh(hqA), w1A, ayA);

        if (iaB != curB) {                     // wave-uniform
            if (curB >= 0) {
                float* p = AGG + (size_t)curB * NB + 2 * lane;
                if (nfB == 0) { atomicAdd(p, axB); atomicAdd(p + 1, ayB); }
                else          { *(float2*)p = make_float2(axB, ayB); }
                ++nfB;
            }
            axB = 0.f; ayB = 0.f;
            curB = iaB;
        }
        axB = fmaf(bfl(hqB), w0B, axB);
        ayB = fmaf(bfh(hqB), w1B, ayB);
    }
    if (curA >= 0) {                           // final flushes: always atomic
        float* p = AGG + (size_t)curA * NB + 2 * lane;
        atomicAdd(p, axA); atomicAdd(p + 1, ayA);
    }
    if (curB >= 0) {
        float* p = AGG + (size_t)curB * NB + 2 * lane;
        atomicAdd(p, axB); atomicAdd(p + 1, ayB);
    }
}

// ---- k_fuse: X (+)= ssp(AGG@W1+b1)@W2+b2, zero AGG behind read,
//      then HB = bf16(X_new @ in2f_next) ----
template<int FIRST, int LAST>
__global__ __launch_bounds__(256) void k_fuse(float* __restrict__ AGG,
                                              const short* __restrict__ img1,
                                              const float* __restrict__ b1,
                                              const short* __restrict__ img2,
                                              const float* __restrict__ b2,
                                              const short* __restrict__ img0n,
                                              const int* __restrict__ z,
                                              const float* __restrict__ emb,
                                              float* __restrict__ X,
                                              unsigned short* __restrict__ HB) {
    __shared__ short POOL[16384];              // 32 KB
    short* Ah = POOL;
    short* Th = POOL;
    short* Wh = POOL + 8192;

    int tid = threadIdx.x;
    int wave = tid >> 6, lane = tid & 63;
    int wr = (wave & 1) * 32, wc = (wave >> 1) * 64;
    int row0 = blockIdx.x * 64;

    fx4 accT[2][4];
    #pragma unroll
    for (int s = 0; s < 2; ++s)
        #pragma unroll
        for (int c = 0; c < 4; ++c)
            accT[s][c] = (fx4){0.f, 0.f, 0.f, 0.f};
    for (int kc = 0; kc < 2; ++kc) {
        if (kc) __syncthreads();
        stage_A_agg<!LAST>(AGG, row0, kc, Ah, tid);
        stage_W(img1 + kc * 8192, Wh, tid);
        __syncthreads();
        g_compute(Ah, 0, Wh, wr, wc, lane, accT);
    }
    __syncthreads();

    #pragma unroll
    for (int s = 0; s < 2; ++s)
        #pragma unroll
        for (int c = 0; c < 4; ++c) {
            int colg = wc + c * 16 + (lane & 15);
            float bv = b1[colg];
            int kc2 = colg >> 6, kl = colg & 63;
            #pragma unroll
            for (int reg = 0; reg < 4; ++reg) {
                int rl = wr + s * 16 + (lane >> 4) * 4 + reg;
                float t = ssp_f(accT[s][c][reg] + bv);
                Th[kc2 * 4096 + rl * 64 + (kl ^ ((rl & 7) << 3))] = (short)bf16_rne(t);
            }
        }
    stage_W(img2, Wh, tid);
    __syncthreads();

    fx4 accV[2][4];
    #pragma unroll
    for (int s = 0; s < 2; ++s)
        #pragma unroll
        for (int c = 0; c < 4; ++c)
            accV[s][c] = (fx4){0.f, 0.f, 0.f, 0.f};
    g_compute(Th, 0, Wh, wr, wc, lane, accV);
    __syncthreads();
    stage_W(img2 + 8192, Wh, tid);
    __syncthreads();
    g_compute(Th, 4096, Wh, wr, wc, lane, accV);
    __syncthreads();

    #pragma unroll
    for (int s = 0; s < 2; ++s)
        #pragma unroll
        for (int c = 0; c < 4; ++c) {
            int colg = wc + c * 16 + (lane & 15);
            float bv = b2[colg];
            int kc2 = colg >> 6, kl = colg & 63;
            #pragma unroll
            for (int reg = 0; reg < 4; ++reg) {
                int rowg = row0 + wr + s * 16 + (lane >> 4) * 4 + reg;
                size_t o = (size_t)rowg * NB + colg;
                float xo;
                if (FIRST) xo = emb[(size_t)z[rowg] * NB + colg];
                else       xo = X[o];
                float xn = xo + accV[s][c][reg] + bv;
                X[o] = xn;
                if (!LAST) {
                    int rl = wr + s * 16 + (lane >> 4) * 4 + reg;
                    Th[kc2 * 4096 + rl * 64 + (kl ^ ((rl & 7) << 3))] = (short)bf16_rne(xn);
                }
            }
        }
    if (LAST) return;

    stage_W(img0n, Wh, tid);
    __syncthreads();
    fx4 accH[2][4];
    #pragma unroll
    for (int s = 0; s < 2; ++s)
        #pragma unroll
        for (int c = 0; c < 4; ++c)
            accH[s][c] = (fx4){0.f, 0.f, 0.f, 0.f};
    g_compute(Th, 0, Wh, wr, wc, lane, accH);
    __syncthreads();
    stage_W(img0n + 8192, Wh, tid);
    __syncthreads();
    g_compute(Th, 4096, Wh, wr, wc, lane, accH);

    #pragma unroll
    for (int s = 0; s < 2; ++s)
        #pragma unroll
        for (int c = 0; c < 4; ++c) {
            int colg = wc + c * 16 + (lane & 15);
            #pragma unroll
            for (int reg = 0; reg < 4; ++reg) {
                int rowg = row0 + wr + s * 16 + (lane >> 4) * 4 + reg;
                HB[(size_t)rowg * NB + colg] = bf16_rne(accH[s][c][reg]);
            }
        }
}

extern "C" void kernel_launch(void* const* d_in, const int* in_sizes, int n_in,
                              void* d_out, int out_size, void* d_ws, size_t ws_size,
                              hipStream_t stream) {
    const int*   z    = (const int*)  d_in[0];
    const float* rij  = (const float*)d_in[1];
    const int*   ii   = (const int*)  d_in[2];
    const int*   jj   = (const int*)  d_in[3];
    const float* emb  = (const float*)d_in[4];
    const float* in2f = (const float*)d_in[5];
    const float* fW1  = (const float*)d_in[6];
    const float* fb1  = (const float*)d_in[7];
    const float* fW2  = (const float*)d_in[8];
    const float* fb2  = (const float*)d_in[9];
    const float* oW1  = (const float*)d_in[10];
    const float* ob1  = (const float*)d_in[11];
    const float* oW2  = (const float*)d_in[12];
    const float* ob2  = (const float*)d_in[13];

    const int NXF = N_ATOMS * NB;

    float* X = (float*)d_out;
    unsigned short* HB   = (unsigned short*)d_ws;               // [N_ATOMS][NB] bf16
    float*          AGG  = (float*)(HB + (size_t)NXF);          // [N_ATOMS][NB] fp32
    float*          U    = AGG + (size_t)NXF;                   // [N_EDGES] u = d*TSCALE
    unsigned short* Tab0 = (unsigned short*)(U + N_EDGES);      // [258][NB] bf16
    unsigned short* Tab1 = Tab0 + (size_t)TROWS * NB;
    short*          Wimg = (short*)(Tab1 + (size_t)TROWS * NB); // 9 x 16384 (w=0 unused)

    k_pre0<<<P0_GEMM + P0_ZERO + P0_TAB + P0_DST + P0_WPR, 256, 0, stream>>>(
        z, emb, rij, in2f, oW1, oW2,
        fW1, fb1, fW2, fb2, HB, Tab0, AGG, U, Wimg);

    for (int l = 0; l < NLAYERS; ++l) {
        unsigned short* TabCur = (l & 1) ? Tab1 : Tab0;
        unsigned short* TabNxt = (l & 1) ? Tab0 : Tab1;
        int ln = (l < NLAYERS - 1) ? l + 1 : 0;
        int grid_e = EBLKS + ((l < NLAYERS - 1) ? TABBLKS : 0);

        k_edge<<<grid_e, 256, 0, stream>>>(U, ii, jj,
                                           (const unsigned*)HB,
                                           (const unsigned*)TabCur,
                                           AGG,
                                           fW1 + (size_t)ln * NRBF * NB,
                                           fb1 + (size_t)ln * NB,
                                           fW2 + (size_t)ln * NB * NB,
                                           fb2 + (size_t)ln * NB,
                                           TabNxt);

        const short* img1  = Wimg + (size_t)(l * 3 + 1) * 16384;
        const short* img2  = Wimg + (size_t)(l * 3 + 2) * 16384;
        const short* img0n = Wimg + (size_t)((l + 1 < NLAYERS ? (l + 1) * 3 : 3)) * 16384;

        if (l == 0)
            k_fuse<1, 0><<<N_ATOMS / 64, 256, 0, stream>>>(AGG, img1, ob1 + (size_t)l * NB,
                                                           img2, ob2 + (size_t)l * NB,
                                                           img0n, z, emb, X, HB);
        else if (l < NLAYERS - 1)
            k_fuse<0, 0><<<N_ATOMS / 64, 256, 0, stream>>>(AGG, img1, ob1 + (size_t)l * NB,
                                                           img2, ob2 + (size_t)l * NB,
                                                           img0n, z, emb, X, HB);
        else
            k_fuse<0, 1><<<N_ATOMS / 64, 256, 0, stream>>>(AGG, img1, ob1 + (size_t)l * NB,
                                                           img2, ob2 + (size_t)l * NB,
                                                           img0n, z, emb, X, HB);
    }
}

// Round 16
// 202.861 us; speedup vs baseline: 1.2700x; 1.0572x over previous
//
#include <hip/hip_runtime.h>
#include <math.h>

#define N_ATOMS 40000
#define N_EDGES 640000
#define NB      128
#define NRBF    20
#define NLAYERS 3
#define CUTOFF  5.0f
#define DELTA   (CUTOFF / 19.0f)
#define RBF_COEFF (-0.5f / (DELTA * DELTA))
#define LN2F    0.69314718055994531f

#define KTAB    256                     // lerp intervals over [0, CUTOFF]
#define TROWS   (KTAB + 2)              // rows 256,257 exact zero
#define TSCALE  ((float)KTAB / CUTOFF)
#define EPB     512                     // edges per block (4 waves x 2 streams x 64)
#define EBLKS   (N_EDGES / EPB)         // 1250
#define TABBLKS (TROWS / 2)             // 129

typedef __attribute__((ext_vector_type(8))) short bf16x8;
typedef __attribute__((ext_vector_type(4))) short bf16x4;
typedef __attribute__((ext_vector_type(4))) float fx4;

__device__ __forceinline__ float ssp_f(float x) {
    return fmaxf(x, 0.f) + __logf(1.f + __expf(-fabsf(x))) - LN2F;
}

__device__ __forceinline__ unsigned short bf16_rne(float x) {
    unsigned u = __float_as_uint(x);
    unsigned r = u + 0x7fffu + ((u >> 16) & 1u);
    return (unsigned short)(r >> 16);
}

__device__ __forceinline__ float bfl(unsigned u) { return __uint_as_float(u << 16); }
__device__ __forceinline__ float bfh(unsigned u) { return __uint_as_float(u & 0xffff0000u); }

// ---- GEMM building blocks (plain bf16) ----

// stage AGG chunk and zero it behind the read (next-layer prep)
template<int ZERO>
__device__ __forceinline__ void stage_A_agg(float* __restrict__ A, int row0, int kc,
                                            short* Ah, int tid) {
    #pragma unroll
    for (int it = 0; it < 4; ++it) {
        int idx4 = tid + it * 256;
        int r = idx4 >> 4, kq = (idx4 & 15) << 2;
        float* src = A + (size_t)(row0 + r) * NB + kc * 64 + kq;
        float4 v = *(const float4*)src;
        if (ZERO) *(float4*)src = make_float4(0.f, 0.f, 0.f, 0.f);
        bf16x4 hs;
        const float* vf = (const float*)&v;
        #pragma unroll
        for (int j = 0; j < 4; ++j) hs[j] = (short)bf16_rne(vf[j]);
        int wi = r * 64 + (kq ^ ((r & 7) << 3));
        *(bf16x4*)(Ah + wi) = hs;
    }
}

// stage A from embedding gather (layer 0 GEMM0)
__device__ __forceinline__ void stage_A_emb(const float* __restrict__ emb,
                                            const int* __restrict__ z, int row0, int kc,
                                            short* Ah, int tid) {
    #pragma unroll
    for (int it = 0; it < 4; ++it) {
        int idx4 = tid + it * 256;
        int r = idx4 >> 4, kq = (idx4 & 15) << 2;
        int zr = z[row0 + r];
        float4 v = *(const float4*)(emb + (size_t)zr * NB + kc * 64 + kq);
        bf16x4 hs;
        const float* vf = (const float*)&v;
        #pragma unroll
        for (int j = 0; j < 4; ++j) hs[j] = (short)bf16_rne(vf[j]);
        int wi = r * 64 + (kq ^ ((r & 7) << 3));
        *(bf16x4*)(Ah + wi) = hs;
    }
}

// copy one pre-swizzled weight chunk image (128 cols x 64 k) to LDS
__device__ __forceinline__ void stage_W(const short* __restrict__ imgh,
                                        short* Wh, int tid) {
    #pragma unroll
    for (int it = 0; it < 4; ++it) {
        int i = tid + it * 256;
        ((bf16x8*)Wh)[i] = ((const bf16x8*)imgh)[i];
    }
}

// stage W chunk directly from fp32 W[k][col] (layer-0 GEMM0 only)
__device__ __forceinline__ void stage_W_f32(const float* __restrict__ W, int kc,
                                            short* Wh, int tid) {
    #pragma unroll
    for (int it = 0; it < 8; ++it) {
        int i = tid + it * 256;
        int kl = i >> 5;
        int c0 = (i & 31) << 2;
        float4 v = *(const float4*)(W + (size_t)(kc * 64 + kl) * NB + c0);
        const float* vf = (const float*)&v;
        #pragma unroll
        for (int j = 0; j < 4; ++j) {
            int col = c0 + j;
            Wh[col * 64 + (kl ^ ((col & 7) << 3))] = (short)bf16_rne(vf[j]);
        }
    }
}

// one K=64 chunk of bf16 MFMA: acc += A_chunk @ W_chunk (16 MFMA/wave)
__device__ __forceinline__ void g_compute(const short* AH, int choff,
                                          const short* Wh,
                                          int wr, int wc, int lane, fx4 acc[2][4]) {
    #pragma unroll
    for (int ks = 0; ks < 2; ++ks) {
        int kb = ks * 32 + (lane >> 4) * 8;
        bf16x8 a_h[2];
        #pragma unroll
        for (int s = 0; s < 2; ++s) {
            int r = wr + s * 16 + (lane & 15);
            int idx = choff + r * 64 + (kb ^ ((r & 7) << 3));
            a_h[s] = *(const bf16x8*)(AH + idx);
        }
        #pragma unroll
        for (int c = 0; c < 4; ++c) {
            int col = wc + c * 16 + (lane & 15);
            int idx = col * 64 + (kb ^ ((col & 7) << 3));
            bf16x8 b_h = *(const bf16x8*)(Wh + idx);
            #pragma unroll
            for (int s = 0; s < 2; ++s)
                acc[s][c] = __builtin_amdgcn_mfma_f32_16x16x32_bf16(a_h[s], b_h, acc[s][c], 0, 0, 0);
        }
    }
}

// ---- k_pre0: layer-0 GEMM0 + zero AGG + table0 + dist + wprep(w=1..8) ----
#define P0_GEMM 625
#define P0_ZERO 1250
#define P0_TAB  TABBLKS
#define P0_DST  625
#define P0_WPR  64
__global__ __launch_bounds__(256) void k_pre0(const int* __restrict__ z,
                                              const float* __restrict__ emb,
                                              const float* __restrict__ r_ij,
                                              const float* __restrict__ in2f,
                                              const float* __restrict__ oW1,
                                              const float* __restrict__ oW2,
                                              const float* __restrict__ fW1,
                                              const float* __restrict__ fb1,
                                              const float* __restrict__ fW2,
                                              const float* __restrict__ fb2,
                                              unsigned short* __restrict__ HB,
                                              unsigned short* __restrict__ TabB,
                                              float* __restrict__ AGG,
                                              float* __restrict__ U,
                                              short* __restrict__ Wimg) {
    __shared__ short APOOL[12288];               // 24 KB
    int bid = blockIdx.x, tid = threadIdx.x;

    if (bid < P0_GEMM) {
        short* Ah = APOOL;
        short* Wh = APOOL + 4096;
        int wave = tid >> 6, lane = tid & 63;
        int wr = (wave & 1) * 32, wc = (wave >> 1) * 64;
        int row0 = bid * 64;
        fx4 acc[2][4];
        #pragma unroll
        for (int s = 0; s < 2; ++s)
            #pragma unroll
            for (int c = 0; c < 4; ++c)
                acc[s][c] = (fx4){0.f, 0.f, 0.f, 0.f};
        for (int kc = 0; kc < 2; ++kc) {
            if (kc) __syncthreads();
            stage_A_emb(emb, z, row0, kc, Ah, tid);
            stage_W_f32(in2f, kc, Wh, tid);
            __syncthreads();
            g_compute(Ah, 0, Wh, wr, wc, lane, acc);
        }
        #pragma unroll
        for (int s = 0; s < 2; ++s)
            #pragma unroll
            for (int c = 0; c < 4; ++c) {
                int colg = wc + c * 16 + (lane & 15);
                #pragma unroll
                for (int reg = 0; reg < 4; ++reg) {
                    int rowg = row0 + wr + s * 16 + (lane >> 4) * 4 + reg;
                    HB[(size_t)rowg * NB + colg] = bf16_rne(acc[s][c][reg]);
                }
            }
    } else if (bid < P0_GEMM + P0_ZERO) {
        int base = (bid - P0_GEMM) * 4096 + tid * 16;
        float4 zv = make_float4(0.f, 0.f, 0.f, 0.f);
        float4* p = (float4*)(AGG + base);
        p[0] = zv; p[1] = zv; p[2] = zv; p[3] = zv;
    } else if (bid < P0_GEMM + P0_ZERO + P0_TAB) {
        int tb = bid - (P0_GEMM + P0_ZERO);
        int half = tid >> 7, f = tid & 127;
        int r = tb * 2 + half;                   // 0..257
        float* tl = (float*)APOOL;               // [2][128] ssp intermediates
        float val = 0.f;
        float d = (float)r * (CUTOFF / (float)KTAB);
        if (r < KTAB) {
            float a = fb1[f];
            #pragma unroll
            for (int q = 0; q < NRBF; ++q) {
                float dr = d - (float)q * DELTA;
                a += __expf(RBF_COEFF * dr * dr) * fW1[q * NB + f];
            }
            tl[half * NB + f] = ssp_f(a);
        }
        __syncthreads();
        if (r < KTAB) {
            float w = fb2[f];
            #pragma unroll 4
            for (int k = 0; k < NB; ++k) w += tl[half * NB + k] * fW2[k * NB + f];
            float rc = 0.5f * (__cosf(d * ((float)M_PI / CUTOFF)) + 1.f);
            val = w * rc;
        }
        TabB[(size_t)r * NB + f] = bf16_rne(val);
    } else if (bid < P0_GEMM + P0_ZERO + P0_TAB + P0_DST) {
        int e = (bid - (P0_GEMM + P0_ZERO + P0_TAB)) * 1024 + tid * 4;
        const float4* rv = (const float4*)(r_ij + (size_t)e * 3);
        float4 a = rv[0], b = rv[1], c = rv[2];
        float d0 = sqrtf(a.x * a.x + a.y * a.y + a.z * a.z);
        float d1 = sqrtf(a.w * a.w + b.x * b.x + b.y * b.y);
        float d2 = sqrtf(b.z * b.z + b.w * b.w + c.x * c.x);
        float d3 = sqrtf(c.y * c.y + c.z * c.z + c.w * c.w);
        *(float4*)(U + e) = make_float4(d0 * TSCALE, d1 * TSCALE, d2 * TSCALE, d3 * TSCALE);
    } else {
        int b2 = bid - (P0_GEMM + P0_ZERO + P0_TAB + P0_DST);   // 0..63
        int w = 1 + (b2 >> 3), seg = b2 & 7;                    // images 1..8
        int layer = w / 3, which = w % 3;
        const float* W = (which == 0 ? in2f : which == 1 ? oW1 : oW2)
                         + (size_t)layer * NB * NB;
        short* hi = Wimg + (size_t)w * 16384;
        int i0 = seg * 2048;
        #pragma unroll
        for (int ofs = 0; ofs < 2048; ofs += 256) {
            int i = i0 + ofs + tid;
            int k = i >> 7, col = i & 127;
            int kc = k >> 6, kl = k & 63;
            hi[kc * 8192 + col * 64 + (kl ^ ((col & 7) << 3))] = (short)bf16_rne(W[i]);
        }
    }
}

// ---- edge kernel: dual-stream (2 x 64-edge runs per wave), two-row bf16 lerp,
//      boundary atomics + interior plain stores; appended next-layer table ----
__global__ __launch_bounds__(256) void k_edge(const float* __restrict__ U,
                                              const int* __restrict__ idx_i,
                                              const int* __restrict__ idx_j,
                                              const unsigned* __restrict__ HBv,
                                              const unsigned* __restrict__ TabU,
                                              float* __restrict__ AGG,
                                              const float* __restrict__ nW1,
                                              const float* __restrict__ nb1,
                                              const float* __restrict__ nW2,
                                              const float* __restrict__ nb2,
                                              unsigned short* __restrict__ TabN) {
    __shared__ float u_s[EPB];
    __shared__ int   i_s[EPB];
    __shared__ int   j_s[EPB];
    __shared__ float t_lds[256];
    int tid = threadIdx.x;
    int bid = blockIdx.x;

    if (bid >= EBLKS) {                        // next-layer table block
        int tb = bid - EBLKS;
        int half = tid >> 7, f = tid & 127;
        int r = tb * 2 + half;                 // 0..257
        float val = 0.f;
        float d = (float)r * (CUTOFF / (float)KTAB);
        if (r < KTAB) {
            float a = nb1[f];
            #pragma unroll
            for (int q = 0; q < NRBF; ++q) {
                float dr = d - (float)q * DELTA;
                a += __expf(RBF_COEFF * dr * dr) * nW1[q * NB + f];
            }
            t_lds[half * NB + f] = ssp_f(a);
        }
        __syncthreads();
        if (r < KTAB) {
            float w = nb2[f];
            #pragma unroll 4
            for (int k = 0; k < NB; ++k) w += t_lds[half * NB + k] * nW2[k * NB + f];
            float rc = 0.5f * (__cosf(d * ((float)M_PI / CUTOFF)) + 1.f);
            val = w * rc;
        }
        TabN[(size_t)r * NB + f] = bf16_rne(val);
        return;
    }

    int e0 = bid * EPB;
    u_s[tid]       = U[e0 + tid];
    u_s[tid + 256] = U[e0 + 256 + tid];
    i_s[tid]       = idx_i[e0 + tid];
    i_s[tid + 256] = idx_i[e0 + 256 + tid];
    j_s[tid]       = idx_j[e0 + tid];
    j_s[tid + 256] = idx_j[e0 + 256 + tid];
    __syncthreads();

    int wave = tid >> 6, lane = tid & 63;
    int wbase = wave << 7;                     // 128 edges per wave

    float axA = 0.f, ayA = 0.f, axB = 0.f, ayB = 0.f;
    int curA = -1, curB = -1;
    int nfA = 0, nfB = 0;

    #pragma unroll 2
    for (int t = 0; t < 64; ++t) {
        int eA = wbase + t;
        int eB = wbase + 64 + t;
        float uA = u_s[eA], uB = u_s[eB];
        int   iaA = i_s[eA], iaB = i_s[eB];
        int   jaA = j_s[eA], jaB = j_s[eB];

        int kA = (int)uA; kA = (kA > KTAB) ? KTAB : kA;
        int kB = (int)uB; kB = (kB > KTAB) ? KTAB : kB;
        float frA = uA - (float)kA;
        float frB = uB - (float)kB;

        unsigned v0A = TabU[kA * 64 + lane];
        unsigned v1A = TabU[kA * 64 + 64 + lane];
        unsigned v0B = TabU[kB * 64 + lane];
        unsigned v1B = TabU[kB * 64 + 64 + lane];
        unsigned hqA = HBv[jaA * 64 + lane];
        unsigned hqB = HBv[jaB * 64 + lane];

        float w0A = fmaf(frA, bfl(v1A) - bfl(v0A), bfl(v0A));
        float w1A = fmaf(frA, bfh(v1A) - bfh(v0A), bfh(v0A));
        float w0B = fmaf(frB, bfl(v1B) - bfl(v0B), bfl(v0B));
        float w1B = fmaf(frB, bfh(v1B) - bfh(v0B), bfh(v0B));

        if (iaA != curA) {                     // wave-uniform
            if (curA >= 0) {
                float* p = AGG + (size_t)curA * NB + 2 * lane;
                if (nfA == 0) { atomicAdd(p, axA); atomicAdd(p + 1, ayA); }
                else          { *(float2*)p = make_float2(axA, ayA); }
                ++nfA;
            }
            axA = 0.f; ayA = 0.f;
            curA = iaA;
        }
        axA = fmaf(bfl(hqA), w0A, axA);
        ayA = fmaf(bfh(hqA), w1A, ayA);

        if (iaB != curB) {                     // wave-uniform
            if (curB >= 0) {
                float* p = AGG + (size_t)curB * NB + 2 * lane;
                if (nfB == 0) { atomicAdd(p, axB); atomicAdd(p + 1, ayB); }
                else          { *(float2*)p = make_float2(axB, ayB); }
                ++nfB;
            }
            axB = 0.f; ayB = 0.f;
            curB = iaB;
        }
        axB = fmaf(bfl(hqB), w0B, axB);
        ayB = fmaf(bfh(hqB), w1B, ayB);
    }
    if (curA >= 0) {                           // final flushes: always atomic
        float* p = AGG + (size_t)curA * NB + 2 * lane;
        atomicAdd(p, axA); atomicAdd(p + 1, ayA);
    }
    if (curB >= 0) {
        float* p = AGG + (size_t)curB * NB + 2 * lane;
        atomicAdd(p, axB); atomicAdd(p + 1, ayB);
    }
}

// ---- k_fuse: X (+)= ssp(AGG@W1+b1)@W2+b2, zero AGG behind read,
//      then HB = bf16(X_new @ in2f_next) ----
template<int FIRST, int LAST>
__global__ __launch_bounds__(256) void k_fuse(float* __restrict__ AGG,
                                              const short* __restrict__ img1,
                                              const float* __restrict__ b1,
                                              const short* __restrict__ img2,
                                              const float* __restrict__ b2,
                                              const short* __restrict__ img0n,
                                              const int* __restrict__ z,
                                              const float* __restrict__ emb,
                                              float* __restrict__ X,
                                              unsigned short* __restrict__ HB) {
    __shared__ short POOL[16384];              // 32 KB
    short* Ah = POOL;
    short* Th = POOL;
    short* Wh = POOL + 8192;

    int tid = threadIdx.x;
    int wave = tid >> 6, lane = tid & 63;
    int wr = (wave & 1) * 32, wc = (wave >> 1) * 64;
    int row0 = blockIdx.x * 64;

    fx4 accT[2][4];
    #pragma unroll
    for (int s = 0; s < 2; ++s)
        #pragma unroll
        for (int c = 0; c < 4; ++c)
            accT[s][c] = (fx4){0.f, 0.f, 0.f, 0.f};
    for (int kc = 0; kc < 2; ++kc) {
        if (kc) __syncthreads();
        stage_A_agg<!LAST>(AGG, row0, kc, Ah, tid);
        stage_W(img1 + kc * 8192, Wh, tid);
        __syncthreads();
        g_compute(Ah, 0, Wh, wr, wc, lane, accT);
    }
    __syncthreads();

    #pragma unroll
    for (int s = 0; s < 2; ++s)
        #pragma unroll
        for (int c = 0; c < 4; ++c) {
            int colg = wc + c * 16 + (lane & 15);
            float bv = b1[colg];
            int kc2 = colg >> 6, kl = colg & 63;
            #pragma unroll
            for (int reg = 0; reg < 4; ++reg) {
                int rl = wr + s * 16 + (lane >> 4) * 4 + reg;
                float t = ssp_f(accT[s][c][reg] + bv);
                Th[kc2 * 4096 + rl * 64 + (kl ^ ((rl & 7) << 3))] = (short)bf16_rne(t);
            }
        }
    stage_W(img2, Wh, tid);
    __syncthreads();

    fx4 accV[2][4];
    #pragma unroll
    for (int s = 0; s < 2; ++s)
        #pragma unroll
        for (int c = 0; c < 4; ++c)
            accV[s][c] = (fx4){0.f, 0.f, 0.f, 0.f};
    g_compute(Th, 0, Wh, wr, wc, lane, accV);
    __syncthreads();
    stage_W(img2 + 8192, Wh, tid);
    __syncthreads();
    g_compute(Th, 4096, Wh, wr, wc, lane, accV);
    __syncthreads();

    #pragma unroll
    for (int s = 0; s < 2; ++s)
        #pragma unroll
        for (int c = 0; c < 4; ++c) {
            int colg = wc + c * 16 + (lane & 15);
            float bv = b2[colg];
            int kc2 = colg >> 6, kl = colg & 63;
            #pragma unroll
            for (int reg = 0; reg < 4; ++reg) {
                int rowg = row0 + wr + s * 16 + (lane >> 4) * 4 + reg;
                size_t o = (size_t)rowg * NB + colg;
                float xo;
                if (FIRST) xo = emb[(size_t)z[rowg] * NB + colg];
                else       xo = X[o];
                float xn = xo + accV[s][c][reg] + bv;
                X[o] = xn;
                if (!LAST) {
                    int rl = wr + s * 16 + (lane >> 4) * 4 + reg;
                    Th[kc2 * 4096 + rl * 64 + (kl ^ ((rl & 7) << 3))] = (short)bf16_rne(xn);
                }
            }
        }
    if (LAST) return;

    stage_W(img0n, Wh, tid);
    __syncthreads();
    fx4 accH[2][4];
    #pragma unroll
    for (int s = 0; s < 2; ++s)
        #pragma unroll
        for (int c = 0; c < 4; ++c)
            accH[s][c] = (fx4){0.f, 0.f, 0.f, 0.f};
    g_compute(Th, 0, Wh, wr, wc, lane, accH);
    __syncthreads();
    stage_W(img0n + 8192, Wh, tid);
    __syncthreads();
    g_compute(Th, 4096, Wh, wr, wc, lane, accH);

    #pragma unroll
    for (int s = 0; s < 2; ++s)
        #pragma unroll
        for (int c = 0; c < 4; ++c) {
            int colg = wc + c * 16 + (lane & 15);
            #pragma unroll
            for (int reg = 0; reg < 4; ++reg) {
                int rowg = row0 + wr + s * 16 + (lane >> 4) * 4 + reg;
                HB[(size_t)rowg * NB + colg] = bf16_rne(accH[s][c][reg]);
            }
        }
}

extern "C" void kernel_launch(void* const* d_in, const int* in_sizes, int n_in,
                              void* d_out, int out_size, void* d_ws, size_t ws_size,
                              hipStream_t stream) {
    const int*   z    = (const int*)  d_in[0];
    const float* rij  = (const float*)d_in[1];
    const int*   ii   = (const int*)  d_in[2];
    const int*   jj   = (const int*)  d_in[3];
    const float* emb  = (const float*)d_in[4];
    const float* in2f = (const float*)d_in[5];
    const float* fW1  = (const float*)d_in[6];
    const float* fb1  = (const float*)d_in[7];
    const float* fW2  = (const float*)d_in[8];
    const float* fb2  = (const float*)d_in[9];
    const float* oW1  = (const float*)d_in[10];
    const float* ob1  = (const float*)d_in[11];
    const float* oW2  = (const float*)d_in[12];
    const float* ob2  = (const float*)d_in[13];

    const int NXF = N_ATOMS * NB;

    float* X = (float*)d_out;
    unsigned short* HB   = (unsigned short*)d_ws;               // [N_ATOMS][NB] bf16
    float*          AGG  = (float*)(HB + (size_t)NXF);          // [N_ATOMS][NB] fp32
    float*          U    = AGG + (size_t)NXF;                   // [N_EDGES] u = d*TSCALE
    unsigned short* Tab0 = (unsigned short*)(U + N_EDGES);      // [258][NB] bf16
    unsigned short* Tab1 = Tab0 + (size_t)TROWS * NB;
    short*          Wimg = (short*)(Tab1 + (size_t)TROWS * NB); // 9 x 16384 (w=0 unused)

    k_pre0<<<P0_GEMM + P0_ZERO + P0_TAB + P0_DST + P0_WPR, 256, 0, stream>>>(
        z, emb, rij, in2f, oW1, oW2,
        fW1, fb1, fW2, fb2, HB, Tab0, AGG, U, Wimg);

    for (int l = 0; l < NLAYERS; ++l) {
        unsigned short* TabCur = (l & 1) ? Tab1 : Tab0;
        unsigned short* TabNxt = (l & 1) ? Tab0 : Tab1;
        int ln = (l < NLAYERS - 1) ? l + 1 : 0;
        int grid_e = EBLKS + ((l < NLAYERS - 1) ? TABBLKS : 0);

        k_edge<<<grid_e, 256, 0, stream>>>(U, ii, jj,
                                           (const unsigned*)HB,
                                           (const unsigned*)TabCur,
                                           AGG,
                                           fW1 + (size_t)ln * NRBF * NB,
                                           fb1 + (size_t)ln * NB,
                                           fW2 + (size_t)ln * NB * NB,
                                           fb2 + (size_t)ln * NB,
                                           TabNxt);

        const short* img1  = Wimg + (size_t)(l * 3 + 1) * 16384;
        const short* img2  = Wimg + (size_t)(l * 3 + 2) * 16384;
        const short* img0n = Wimg + (size_t)((l + 1 < NLAYERS ? (l + 1) * 3 : 3)) * 16384;

        if (l == 0)
            k_fuse<1, 0><<<N_ATOMS / 64, 256, 0, stream>>>(AGG, img1, ob1 + (size_t)l * NB,
                                                           img2, ob2 + (size_t)l * NB,
                                                           img0n, z, emb, X, HB);
        else if (l < NLAYERS - 1)
            k_fuse<0, 0><<<N_ATOMS / 64, 256, 0, stream>>>(AGG, img1, ob1 + (size_t)l * NB,
                                                           img2, ob2 + (size_t)l * NB,
                                                           img0n, z, emb, X, HB);
        else
            k_fuse<0, 1><<<N_ATOMS / 64, 256, 0, stream>>>(AGG, img1, ob1 + (size_t)l * NB,
                                                           img2, ob2 + (size_t)l * NB,
                                                           img0n, z, emb, X, HB);
    }
}

// Round 17
// 200.589 us; speedup vs baseline: 1.2844x; 1.0113x over previous
//
#include <hip/hip_runtime.h>
#include <math.h>

#define N_ATOMS 40000
#define N_EDGES 640000
#define NB      128
#define NRBF    20
#define NLAYERS 3
#define CUTOFF  5.0f
#define DELTA   (CUTOFF / 19.0f)
#define RBF_COEFF (-0.5f / (DELTA * DELTA))
#define LN2F    0.69314718055994531f

#define KTAB    256                     // lerp intervals over [0, CUTOFF]
#define TROWS   (KTAB + 2)              // rows 256,257 exact zero
#define TSCALE  ((float)KTAB / CUTOFF)
#define EPB     512                     // edges per block (4 waves x 2 streams x 64)
#define EBLKS   (N_EDGES / EPB)         // 1250
#define TABBLKS (TROWS / 2)             // 129

typedef __attribute__((ext_vector_type(8))) short bf16x8;
typedef __attribute__((ext_vector_type(4))) short bf16x4;
typedef __attribute__((ext_vector_type(4))) float fx4;
typedef __attribute__((ext_vector_type(2))) float fx2;

__device__ __forceinline__ float ssp_f(float x) {
    return fmaxf(x, 0.f) + __logf(1.f + __expf(-fabsf(x))) - LN2F;
}

__device__ __forceinline__ unsigned short bf16_rne(float x) {
    unsigned u = __float_as_uint(x);
    unsigned r = u + 0x7fffu + ((u >> 16) & 1u);
    return (unsigned short)(r >> 16);
}

__device__ __forceinline__ unsigned char fp8_rne(float x) {
    return (unsigned char)(__builtin_amdgcn_cvt_pk_fp8_f32(x, x, 0, false) & 0xff);
}

__device__ __forceinline__ float bfl(unsigned u) { return __uint_as_float(u << 16); }
__device__ __forceinline__ float bfh(unsigned u) { return __uint_as_float(u & 0xffff0000u); }

// ---- GEMM building blocks (plain bf16) ----

// stage AGG chunk and zero it behind the read (next-layer prep)
template<int ZERO>
__device__ __forceinline__ void stage_A_agg(float* __restrict__ A, int row0, int kc,
                                            short* Ah, int tid) {
    #pragma unroll
    for (int it = 0; it < 4; ++it) {
        int idx4 = tid + it * 256;
        int r = idx4 >> 4, kq = (idx4 & 15) << 2;
        float* src = A + (size_t)(row0 + r) * NB + kc * 64 + kq;
        float4 v = *(const float4*)src;
        if (ZERO) *(float4*)src = make_float4(0.f, 0.f, 0.f, 0.f);
        bf16x4 hs;
        const float* vf = (const float*)&v;
        #pragma unroll
        for (int j = 0; j < 4; ++j) hs[j] = (short)bf16_rne(vf[j]);
        int wi = r * 64 + (kq ^ ((r & 7) << 3));
        *(bf16x4*)(Ah + wi) = hs;
    }
}

// stage A from embedding gather (layer 0 GEMM0)
__device__ __forceinline__ void stage_A_emb(const float* __restrict__ emb,
                                            const int* __restrict__ z, int row0, int kc,
                                            short* Ah, int tid) {
    #pragma unroll
    for (int it = 0; it < 4; ++it) {
        int idx4 = tid + it * 256;
        int r = idx4 >> 4, kq = (idx4 & 15) << 2;
        int zr = z[row0 + r];
        float4 v = *(const float4*)(emb + (size_t)zr * NB + kc * 64 + kq);
        bf16x4 hs;
        const float* vf = (const float*)&v;
        #pragma unroll
        for (int j = 0; j < 4; ++j) hs[j] = (short)bf16_rne(vf[j]);
        int wi = r * 64 + (kq ^ ((r & 7) << 3));
        *(bf16x4*)(Ah + wi) = hs;
    }
}

// copy one pre-swizzled weight chunk image (128 cols x 64 k) to LDS
__device__ __forceinline__ void stage_W(const short* __restrict__ imgh,
                                        short* Wh, int tid) {
    #pragma unroll
    for (int it = 0; it < 4; ++it) {
        int i = tid + it * 256;
        ((bf16x8*)Wh)[i] = ((const bf16x8*)imgh)[i];
    }
}

// stage W chunk directly from fp32 W[k][col] (layer-0 GEMM0 only)
__device__ __forceinline__ void stage_W_f32(const float* __restrict__ W, int kc,
                                            short* Wh, int tid) {
    #pragma unroll
    for (int it = 0; it < 8; ++it) {
        int i = tid + it * 256;
        int kl = i >> 5;
        int c0 = (i & 31) << 2;
        float4 v = *(const float4*)(W + (size_t)(kc * 64 + kl) * NB + c0);
        const float* vf = (const float*)&v;
        #pragma unroll
        for (int j = 0; j < 4; ++j) {
            int col = c0 + j;
            Wh[col * 64 + (kl ^ ((col & 7) << 3))] = (short)bf16_rne(vf[j]);
        }
    }
}

// one K=64 chunk of bf16 MFMA: acc += A_chunk @ W_chunk (16 MFMA/wave)
__device__ __forceinline__ void g_compute(const short* AH, int choff,
                                          const short* Wh,
                                          int wr, int wc, int lane, fx4 acc[2][4]) {
    #pragma unroll
    for (int ks = 0; ks < 2; ++ks) {
        int kb = ks * 32 + (lane >> 4) * 8;
        bf16x8 a_h[2];
        #pragma unroll
        for (int s = 0; s < 2; ++s) {
            int r = wr + s * 16 + (lane & 15);
            int idx = choff + r * 64 + (kb ^ ((r & 7) << 3));
            a_h[s] = *(const bf16x8*)(AH + idx);
        }
        #pragma unroll
        for (int c = 0; c < 4; ++c) {
            int col = wc + c * 16 + (lane & 15);
            int idx = col * 64 + (kb ^ ((col & 7) << 3));
            bf16x8 b_h = *(const bf16x8*)(Wh + idx);
            #pragma unroll
            for (int s = 0; s < 2; ++s)
                acc[s][c] = __builtin_amdgcn_mfma_f32_16x16x32_bf16(a_h[s], b_h, acc[s][c], 0, 0, 0);
        }
    }
}

// ---- k_pre0: layer-0 GEMM0 + zero AGG + table0 + dist/meta-pack + wprep(w=1..8) ----
#define P0_GEMM 625
#define P0_ZERO 1250
#define P0_TAB  TABBLKS
#define P0_DST  625
#define P0_WPR  64
__global__ __launch_bounds__(256) void k_pre0(const int* __restrict__ z,
                                              const float* __restrict__ emb,
                                              const float* __restrict__ r_ij,
                                              const int* __restrict__ ii,
                                              const int* __restrict__ jj,
                                              const float* __restrict__ in2f,
                                              const float* __restrict__ oW1,
                                              const float* __restrict__ oW2,
                                              const float* __restrict__ fW1,
                                              const float* __restrict__ fb1,
                                              const float* __restrict__ fW2,
                                              const float* __restrict__ fb2,
                                              unsigned char* __restrict__ HB8,
                                              unsigned short* __restrict__ TabB,
                                              float* __restrict__ AGG,
                                              uint2* __restrict__ PK,
                                              short* __restrict__ Wimg) {
    __shared__ short APOOL[12288];               // 24 KB
    int bid = blockIdx.x, tid = threadIdx.x;

    if (bid < P0_GEMM) {
        short* Ah = APOOL;
        short* Wh = APOOL + 4096;
        int wave = tid >> 6, lane = tid & 63;
        int wr = (wave & 1) * 32, wc = (wave >> 1) * 64;
        int row0 = bid * 64;
        fx4 acc[2][4];
        #pragma unroll
        for (int s = 0; s < 2; ++s)
            #pragma unroll
            for (int c = 0; c < 4; ++c)
                acc[s][c] = (fx4){0.f, 0.f, 0.f, 0.f};
        for (int kc = 0; kc < 2; ++kc) {
            if (kc) __syncthreads();
            stage_A_emb(emb, z, row0, kc, Ah, tid);
            stage_W_f32(in2f, kc, Wh, tid);
            __syncthreads();
            g_compute(Ah, 0, Wh, wr, wc, lane, acc);
        }
        #pragma unroll
        for (int s = 0; s < 2; ++s)
            #pragma unroll
            for (int c = 0; c < 4; ++c) {
                int colg = wc + c * 16 + (lane & 15);
                #pragma unroll
                for (int reg = 0; reg < 4; ++reg) {
                    int rowg = row0 + wr + s * 16 + (lane >> 4) * 4 + reg;
                    HB8[(size_t)rowg * NB + colg] = fp8_rne(acc[s][c][reg]);
                }
            }
    } else if (bid < P0_GEMM + P0_ZERO) {
        int base = (bid - P0_GEMM) * 4096 + tid * 16;
        float4 zv = make_float4(0.f, 0.f, 0.f, 0.f);
        float4* p = (float4*)(AGG + base);
        p[0] = zv; p[1] = zv; p[2] = zv; p[3] = zv;
    } else if (bid < P0_GEMM + P0_ZERO + P0_TAB) {
        int tb = bid - (P0_GEMM + P0_ZERO);
        int half = tid >> 7, f = tid & 127;
        int r = tb * 2 + half;                   // 0..257
        float* tl = (float*)APOOL;               // [2][128] ssp intermediates
        float val = 0.f;
        float d = (float)r * (CUTOFF / (float)KTAB);
        if (r < KTAB) {
            float a = fb1[f];
            #pragma unroll
            for (int q = 0; q < NRBF; ++q) {
                float dr = d - (float)q * DELTA;
                a += __expf(RBF_COEFF * dr * dr) * fW1[q * NB + f];
            }
            tl[half * NB + f] = ssp_f(a);
        }
        __syncthreads();
        if (r < KTAB) {
            float w = fb2[f];
            #pragma unroll 4
            for (int k = 0; k < NB; ++k) w += tl[half * NB + k] * fW2[k * NB + f];
            float rc = 0.5f * (__cosf(d * ((float)M_PI / CUTOFF)) + 1.f);
            val = w * rc;
        }
        TabB[(size_t)r * NB + f] = bf16_rne(val);
    } else if (bid < P0_GEMM + P0_ZERO + P0_TAB + P0_DST) {
        int e = (bid - (P0_GEMM + P0_ZERO + P0_TAB)) * 1024 + tid * 4;
        const float4* rv = (const float4*)(r_ij + (size_t)e * 3);
        float4 a = rv[0], b = rv[1], c = rv[2];
        int4 iv = *(const int4*)(ii + e);
        int4 jv = *(const int4*)(jj + e);
        float d0 = sqrtf(a.x * a.x + a.y * a.y + a.z * a.z);
        float d1 = sqrtf(a.w * a.w + b.x * b.x + b.y * b.y);
        float d2 = sqrtf(b.z * b.z + b.w * b.w + c.x * c.x);
        float d3 = sqrtf(c.y * c.y + c.z * c.z + c.w * c.w);
        float u0 = fminf(d0 * TSCALE, (float)KTAB);
        float u1 = fminf(d1 * TSCALE, (float)KTAB);
        float u2 = fminf(d2 * TSCALE, (float)KTAB);
        float u3 = fminf(d3 * TSCALE, (float)KTAB);
        uint4 w0, w1;
        w0.x = __float_as_uint(u0); w0.y = ((unsigned)iv.x << 16) | (unsigned)jv.x;
        w0.z = __float_as_uint(u1); w0.w = ((unsigned)iv.y << 16) | (unsigned)jv.y;
        w1.x = __float_as_uint(u2); w1.y = ((unsigned)iv.z << 16) | (unsigned)jv.z;
        w1.z = __float_as_uint(u3); w1.w = ((unsigned)iv.w << 16) | (unsigned)jv.w;
        *(uint4*)(PK + e) = w0;
        *(uint4*)(PK + e + 2) = w1;
    } else {
        int b2 = bid - (P0_GEMM + P0_ZERO + P0_TAB + P0_DST);   // 0..63
        int w = 1 + (b2 >> 3), seg = b2 & 7;                    // images 1..8
        int layer = w / 3, which = w % 3;
        const float* W = (which == 0 ? in2f : which == 1 ? oW1 : oW2)
                         + (size_t)layer * NB * NB;
        short* hi = Wimg + (size_t)w * 16384;
        int i0 = seg * 2048;
        #pragma unroll
        for (int ofs = 0; ofs < 2048; ofs += 256) {
            int i = i0 + ofs + tid;
            int k = i >> 7, col = i & 127;
            int kc = k >> 6, kl = k & 63;
            hi[kc * 8192 + col * 64 + (kl ^ ((col & 7) << 3))] = (short)bf16_rne(W[i]);
        }
    }
}

// ---- edge kernel: dual-stream (2 x 64-edge runs/wave), fp8 H gather,
//      two-row bf16 lerp, boundary atomics + interior stores; + next table ----
__global__ __launch_bounds__(256) void k_edge(const uint2* __restrict__ PK,
                                              const unsigned short* __restrict__ HB8v,
                                              const unsigned* __restrict__ TabU,
                                              float* __restrict__ AGG,
                                              const float* __restrict__ nW1,
                                              const float* __restrict__ nb1,
                                              const float* __restrict__ nW2,
                                              const float* __restrict__ nb2,
                                              unsigned short* __restrict__ TabN) {
    __shared__ uint2 m_s[EPB];                 // 4 KB
    __shared__ float t_lds[256];
    int tid = threadIdx.x;
    int bid = blockIdx.x;

    if (bid >= EBLKS) {                        // next-layer table block
        int tb = bid - EBLKS;
        int half = tid >> 7, f = tid & 127;
        int r = tb * 2 + half;                 // 0..257
        float val = 0.f;
        float d = (float)r * (CUTOFF / (float)KTAB);
        if (r < KTAB) {
            float a = nb1[f];
            #pragma unroll
            for (int q = 0; q < NRBF; ++q) {
                float dr = d - (float)q * DELTA;
                a += __expf(RBF_COEFF * dr * dr) * nW1[q * NB + f];
            }
            t_lds[half * NB + f] = ssp_f(a);
        }
        __syncthreads();
        if (r < KTAB) {
            float w = nb2[f];
            #pragma unroll 4
            for (int k = 0; k < NB; ++k) w += t_lds[half * NB + k] * nW2[k * NB + f];
            float rc = 0.5f * (__cosf(d * ((float)M_PI / CUTOFF)) + 1.f);
            val = w * rc;
        }
        TabN[(size_t)r * NB + f] = bf16_rne(val);
        return;
    }

    int e0 = bid * EPB;
    m_s[tid]       = PK[e0 + tid];
    m_s[tid + 256] = PK[e0 + 256 + tid];
    __syncthreads();

    int wave = tid >> 6, lane = tid & 63;
    int wbase = wave << 7;                     // 128 edges per wave

    float axA = 0.f, ayA = 0.f, axB = 0.f, ayB = 0.f;
    int curA = -1, curB = -1;
    int nfA = 0, nfB = 0;

    #pragma unroll 2
    for (int t = 0; t < 64; ++t) {
        uint2 mA = m_s[wbase + t];
        uint2 mB = m_s[wbase + 64 + t];

        float uA = __uint_as_float(mA.x);
        float uB = __uint_as_float(mB.x);
        int kA = (int)uA, kB = (int)uB;
        float frA = uA - (float)kA;
        float frB = uB - (float)kB;
        int iaA = (int)(mA.y >> 16), jaA = (int)(mA.y & 0xffffu);
        int iaB = (int)(mB.y >> 16), jaB = (int)(mB.y & 0xffffu);

        unsigned v0A = TabU[kA * 64 + lane];
        unsigned v1A = TabU[kA * 64 + 64 + lane];
        unsigned v0B = TabU[kB * 64 + lane];
        unsigned v1B = TabU[kB * 64 + 64 + lane];
        unsigned hqA = HB8v[jaA * 64 + lane];  // 2 fp8 per lane
        unsigned hqB = HB8v[jaB * 64 + lane];

        float w0A = fmaf(frA, bfl(v1A) - bfl(v0A), bfl(v0A));
        float w1A = fmaf(frA, bfh(v1A) - bfh(v0A), bfh(v0A));
        float w0B = fmaf(frB, bfl(v1B) - bfl(v0B), bfl(v0B));
        float w1B = fmaf(frB, bfh(v1B) - bfh(v0B), bfh(v0B));

        fx2 hA = __builtin_amdgcn_cvt_pk_f32_fp8((int)hqA, false);
        fx2 hB = __builtin_amdgcn_cvt_pk_f32_fp8((int)hqB, false);

        if (iaA != curA) {                     // wave-uniform
            if (curA >= 0) {
                float* p = AGG + (size_t)curA * NB + 2 * lane;
                if (nfA == 0) { atomicAdd(p, axA); atomicAdd(p + 1, ayA); }
                else          { *(float2*)p = make_float2(axA, ayA); }
                ++nfA;
            }
            axA = 0.f; ayA = 0.f;
            curA = iaA;
        }
        axA = fmaf(hA.x, w0A, axA);
        ayA = fmaf(hA.y, w1A, ayA);

        if (iaB != curB) {                     // wave-uniform
            if (curB >= 0) {
                float* p = AGG + (size_t)curB * NB + 2 * lane;
                if (nfB == 0) { atomicAdd(p, axB); atomicAdd(p + 1, ayB); }
                else          { *(float2*)p = make_float2(axB, ayB); }
                ++nfB;
            }
            axB = 0.f; ayB = 0.f;
            curB = iaB;
        }
        axB = fmaf(hB.x, w0B, axB);
        ayB = fmaf(hB.y, w1B, ayB);
    }
    if (curA >= 0) {                           // final flushes: always atomic
        float* p = AGG + (size_t)curA * NB + 2 * lane;
        atomicAdd(p, axA); atomicAdd(p + 1, ayA);
    }
    if (curB >= 0) {
        float* p = AGG + (size_t)curB * NB + 2 * lane;
        atomicAdd(p, axB); atomicAdd(p + 1, ayB);
    }
}

// ---- k_fuse: X (+)= ssp(AGG@W1+b1)@W2+b2, zero AGG behind read,
//      then HB8 = fp8(X_new @ in2f_next) ----
template<int FIRST, int LAST>
__global__ __launch_bounds__(256) void k_fuse(float* __restrict__ AGG,
                                              const short* __restrict__ img1,
                                              const float* __restrict__ b1,
                                              const short* __restrict__ img2,
                                              const float* __restrict__ b2,
                                              const short* __restrict__ img0n,
                                              const int* __restrict__ z,
                                              const float* __restrict__ emb,
                                              float* __restrict__ X,
                                              unsigned char* __restrict__ HB8) {
    __shared__ short POOL[16384];              // 32 KB
    short* Ah = POOL;
    short* Th = POOL;
    short* Wh = POOL + 8192;

    int tid = threadIdx.x;
    int wave = tid >> 6, lane = tid & 63;
    int wr = (wave & 1) * 32, wc = (wave >> 1) * 64;
    int row0 = blockIdx.x * 64;

    fx4 accT[2][4];
    #pragma unroll
    for (int s = 0; s < 2; ++s)
        #pragma unroll
        for (int c = 0; c < 4; ++c)
            accT[s][c] = (fx4){0.f, 0.f, 0.f, 0.f};
    for (int kc = 0; kc < 2; ++kc) {
        if (kc) __syncthreads();
        stage_A_agg<!LAST>(AGG, row0, kc, Ah, tid);
        stage_W(img1 + kc * 8192, Wh, tid);
        __syncthreads();
        g_compute(Ah, 0, Wh, wr, wc, lane, accT);
    }
    __syncthreads();

    #pragma unroll
    for (int s = 0; s < 2; ++s)
        #pragma unroll
        for (int c = 0; c < 4; ++c) {
            int colg = wc + c * 16 + (lane & 15);
            float bv = b1[colg];
            int kc2 = colg >> 6, kl = colg & 63;
            #pragma unroll
            for (int reg = 0; reg < 4; ++reg) {
                int rl = wr + s * 16 + (lane >> 4) * 4 + reg;
                float t = ssp_f(accT[s][c][reg] + bv);
                Th[kc2 * 4096 + rl * 64 + (kl ^ ((rl & 7) << 3))] = (short)bf16_rne(t);
            }
        }
    stage_W(img2, Wh, tid);
    __syncthreads();

    fx4 accV[2][4];
    #pragma unroll
    for (int s = 0; s < 2; ++s)
        #pragma unroll
        for (int c = 0; c < 4; ++c)
            accV[s][c] = (fx4){0.f, 0.f, 0.f, 0.f};
    g_compute(Th, 0, Wh, wr, wc, lane, accV);
    __syncthreads();
    stage_W(img2 + 8192, Wh, tid);
    __syncthreads();
    g_compute(Th, 4096, Wh, wr, wc, lane, accV);
    __syncthreads();

    #pragma unroll
    for (int s = 0; s < 2; ++s)
        #pragma unroll
        for (int c = 0; c < 4; ++c) {
            int colg = wc + c * 16 + (lane & 15);
            float bv = b2[colg];
            int kc2 = colg >> 6, kl = colg & 63;
            #pragma unroll
            for (int reg = 0; reg < 4; ++reg) {
                int rowg = row0 + wr + s * 16 + (lane >> 4) * 4 + reg;
                size_t o = (size_t)rowg * NB + colg;
                float xo;
                if (FIRST) xo = emb[(size_t)z[rowg] * NB + colg];
                else       xo = X[o];
                float xn = xo + accV[s][c][reg] + bv;
                X[o] = xn;
                if (!LAST) {
                    int rl = wr + s * 16 + (lane >> 4) * 4 + reg;
                    Th[kc2 * 4096 + rl * 64 + (kl ^ ((rl & 7) << 3))] = (short)bf16_rne(xn);
                }
            }
        }
    if (LAST) return;

    stage_W(img0n, Wh, tid);
    __syncthreads();
    fx4 accH[2][4];
    #pragma unroll
    for (int s = 0; s < 2; ++s)
        #pragma unroll
        for (int c = 0; c < 4; ++c)
            accH[s][c] = (fx4){0.f, 0.f, 0.f, 0.f};
    g_compute(Th, 0, Wh, wr, wc, lane, accH);
    __syncthreads();
    stage_W(img0n + 8192, Wh, tid);
    __syncthreads();
    g_compute(Th, 4096, Wh, wr, wc, lane, accH);

    #pragma unroll
    for (int s = 0; s < 2; ++s)
        #pragma unroll
        for (int c = 0; c < 4; ++c) {
            int colg = wc + c * 16 + (lane & 15);
            #pragma unroll
            for (int reg = 0; reg < 4; ++reg) {
                int rowg = row0 + wr + s * 16 + (lane >> 4) * 4 + reg;
                HB8[(size_t)rowg * NB + colg] = fp8_rne(accH[s][c][reg]);
            }
        }
}

extern "C" void kernel_launch(void* const* d_in, const int* in_sizes, int n_in,
                              void* d_out, int out_size, void* d_ws, size_t ws_size,
                              hipStream_t stream) {
    const int*   z    = (const int*)  d_in[0];
    const float* rij  = (const float*)d_in[1];
    const int*   ii   = (const int*)  d_in[2];
    const int*   jj   = (const int*)  d_in[3];
    const float* emb  = (const float*)d_in[4];
    const float* in2f = (const float*)d_in[5];
    const float* fW1  = (const float*)d_in[6];
    const float* fb1  = (const float*)d_in[7];
    const float* fW2  = (const float*)d_in[8];
    const float* fb2  = (const float*)d_in[9];
    const float* oW1  = (const float*)d_in[10];
    const float* ob1  = (const float*)d_in[11];
    const float* oW2  = (const float*)d_in[12];
    const float* ob2  = (const float*)d_in[13];

    const int NXF = N_ATOMS * NB;

    float* X = (float*)d_out;
    unsigned char*  HB8  = (unsigned char*)d_ws;                // [N_ATOMS][NB] fp8 (5.12 MB)
    float*          AGG  = (float*)(HB8 + (size_t)NXF);         // [N_ATOMS][NB] fp32
    uint2*          PK   = (uint2*)(AGG + (size_t)NXF);         // [N_EDGES] {u, i<<16|j}
    unsigned short* Tab0 = (unsigned short*)(PK + N_EDGES);     // [258][NB] bf16
    unsigned short* Tab1 = Tab0 + (size_t)TROWS * NB;
    short*          Wimg = (short*)(Tab1 + (size_t)TROWS * NB); // 9 x 16384 (w=0 unused)

    k_pre0<<<P0_GEMM + P0_ZERO + P0_TAB + P0_DST + P0_WPR, 256, 0, stream>>>(
        z, emb, rij, ii, jj, in2f, oW1, oW2,
        fW1, fb1, fW2, fb2, HB8, Tab0, AGG, PK, Wimg);

    for (int l = 0; l < NLAYERS; ++l) {
        unsigned short* TabCur = (l & 1) ? Tab1 : Tab0;
        unsigned short* TabNxt = (l & 1) ? Tab0 : Tab1;
        int ln = (l < NLAYERS - 1) ? l + 1 : 0;
        int grid_e = EBLKS + ((l < NLAYERS - 1) ? TABBLKS : 0);

        k_edge<<<grid_e, 256, 0, stream>>>(PK,
                                           (const unsigned short*)HB8,
                                           (const unsigned*)TabCur,
                                           AGG,
                                           fW1 + (size_t)ln * NRBF * NB,
                                           fb1 + (size_t)ln * NB,
                                           fW2 + (size_t)ln * NB * NB,
                                           fb2 + (size_t)ln * NB,
                                           TabNxt);

        const short* img1  = Wimg + (size_t)(l * 3 + 1) * 16384;
        const short* img2  = Wimg + (size_t)(l * 3 + 2) * 16384;
        const short* img0n = Wimg + (size_t)((l + 1 < NLAYERS ? (l + 1) * 3 : 3)) * 16384;

        if (l == 0)
            k_fuse<1, 0><<<N_ATOMS / 64, 256, 0, stream>>>(AGG, img1, ob1 + (size_t)l * NB,
                                                           img2, ob2 + (size_t)l * NB,
                                                           img0n, z, emb, X, HB8);
        else if (l < NLAYERS - 1)
            k_fuse<0, 0><<<N_ATOMS / 64, 256, 0, stream>>>(AGG, img1, ob1 + (size_t)l * NB,
                                                           img2, ob2 + (size_t)l * NB,
                                                           img0n, z, emb, X, HB8);
        else
            k_fuse<0, 1><<<N_ATOMS / 64, 256, 0, stream>>>(AGG, img1, ob1 + (size_t)l * NB,
                                                           img2, ob2 + (size_t)l * NB,
                                                           img0n, z, emb, X, HB8);
    }
}